// Round 3
// baseline (304.555 us; speedup 1.0000x reference)
//
#include <hip/hip_runtime.h>

#define EPS_BN 1e-5f

typedef __bf16 bf16x8 __attribute__((ext_vector_type(8)));
typedef float f32x4 __attribute__((ext_vector_type(4)));

__device__ __forceinline__ unsigned short f2bf(float f) {
  union { float f; unsigned u; } v; v.f = f;
  unsigned r = v.u + 0x7fffu + ((v.u >> 16) & 1u);
  return (unsigned short)(r >> 16);
}
__device__ __forceinline__ float bf2f(unsigned short h) {
  union { unsigned u; float f; } v; v.u = ((unsigned)h) << 16;
  return v.f;
}

// ---------------- fused prep ----------------
__global__ __launch_bounds__(256) void prep_all(
    const float* __restrict__ w1, const float* __restrict__ w2, const float* __restrict__ woff,
    const float* __restrict__ w3,
    const float* g1, const float* b1, const float* m1, const float* v1,
    const float* g2, const float* b2, const float* m2, const float* v2, const float* bconv2,
    const float* g3, const float* b3, const float* m3, const float* v3,
    unsigned short* __restrict__ w1b, unsigned short* __restrict__ w2r,
    uint4* __restrict__ act1Pz, unsigned short* __restrict__ wob,
    unsigned short* __restrict__ w3b, float* __restrict__ shift3,
    float* s1, float* h1, float* s2, float* h2) {
  int bid = blockIdx.x, tid = threadIdx.x;
  if (bid < 1024) {
    int i = bid * 256 + tid;
    w1b[i] = f2bf(w1[i]);
  } else if (bid < 3328) {
    int i = (bid - 1024) * 256 + tid;
    int o = i / 2304, r = i % 2304;
    int kk = r / 256, c = r % 256;
    w2r[i] = f2bf(w2[(size_t)o * 2304 + c * 9 + kk]);
  } else if (bid < 5640) {
    int i = (bid - 3328) * 256 + tid;
    if (i < 591872) act1Pz[i] = uint4{0, 0, 0, 0};
  } else if (bid < 5928) {
    int i = (bid - 5640) * 256 + tid;
    int o = i / 2304, r = i % 2304;
    int kk = r / 256, c = r % 256;
    wob[i] = (o < 18) ? f2bf(woff[(size_t)o * 2304 + c * 9 + kk]) : (unsigned short)0;
  } else if (bid < 6952) {
    int i = (bid - 5928) * 256 + tid;
    int o = i >> 8;
    float sc = rsqrtf(v3[o] + EPS_BN) * g3[o];
    w3b[i] = f2bf(w3[i] * sc);
  } else if (bid < 6956) {
    int c = (bid - 6952) * 256 + tid;
    float sc = rsqrtf(v3[c] + EPS_BN) * g3[c];
    shift3[c] = b3[c] - m3[c] * sc;
  } else {
    int c = tid;
    float sc1 = rsqrtf(v1[c] + EPS_BN) * g1[c];
    s1[c] = sc1; h1[c] = b1[c] - m1[c] * sc1;
    float sc2 = rsqrtf(v2[c] + EPS_BN) * g2[c];
    s2[c] = sc2; h2[c] = b2[c] + (bconv2[c] - m2[c]) * sc2;
  }
}

// ---------------- x transpose: (B,1024,4096) f32 -> (B*4096, 1024) bf16, packed stores ----------------
__global__ __launch_bounds__(256) void transpose_x(const float* __restrict__ x,
                                                   unsigned short* __restrict__ xT) {
  __shared__ float t[32][33];
  int b = blockIdx.z;
  int p0 = blockIdx.x * 32, c0 = blockIdx.y * 32;
  int tx = threadIdx.x & 31, ty = threadIdx.x >> 5;
  const float* xb = x + (size_t)b * 1024 * 4096;
#pragma unroll
  for (int j = 0; j < 4; ++j) {
    int c = c0 + ty + j * 8;
    t[ty + j * 8][tx] = xb[(size_t)c * 4096 + p0 + tx];
  }
  __syncthreads();
  unsigned short* xTb = xT + (size_t)b * 4096 * 1024;
  int pl = threadIdx.x >> 3;        // 0..31
  int cl = (threadIdx.x & 7) * 4;   // 0..28
  float v0 = t[cl][pl], v1 = t[cl + 1][pl], v2 = t[cl + 2][pl], v3 = t[cl + 3][pl];
  uint2 pk;
  pk.x = (unsigned)f2bf(v0) | ((unsigned)f2bf(v1) << 16);
  pk.y = (unsigned)f2bf(v2) | ((unsigned)f2bf(v3) << 16);
  *(uint2*)(xTb + (size_t)(p0 + pl) * 1024 + c0 + cl) = pk;
}

// ---------------- K-split MFMA GEMM -> bf16 partials (T4 counted-vmcnt pipeline) ----------------
__global__ __launch_bounds__(256) void gemm_split(
    const unsigned short* __restrict__ A, const unsigned short* __restrict__ Bm,
    unsigned short* __restrict__ part, int M, int N, int K, int KH) {
  __shared__ __align__(16) char blob[16896];              // sA0|sB0, tbuf aliases
  __shared__ __align__(16) unsigned short sA1[4096];
  __shared__ __align__(16) unsigned short sB1[4096];
  unsigned short* sA0 = (unsigned short*)blob;
  unsigned short* sB0 = (unsigned short*)(blob + 8192);
  float* tbuf = (float*)blob;                             // epilogue only
  int tid = threadIdx.x, lane = tid & 63, wv = tid >> 6;
  int z = blockIdx.z;
  int m0 = blockIdx.y * 128, n0 = blockIdx.x * 128;
  f32x4 acc[4][4] = {};
  int rowA = tid >> 2;
  int kcol = (tid & 3) * 8;
  int wm = wv & 1, wn = wv >> 1;
  int lane15 = lane & 15, quad8 = (lane >> 4) * 8, quad = lane >> 4;

#define GS_STAGE(dA, dB, K0)                                                              \
  {                                                                                       \
    int k0_ = (K0);                                                                       \
    _Pragma("unroll") for (int r = 0; r < 2; ++r) {                                       \
      const unsigned short* gp = A + (size_t)(m0 + r * 64 + rowA) * K + k0_ + kcol;       \
      __builtin_amdgcn_global_load_lds((const __attribute__((address_space(1))) void*)gp, \
          (__attribute__((address_space(3))) void*)&(dA)[r * 2048 + wv * 512], 16, 0, 0); \
    }                                                                                     \
    _Pragma("unroll") for (int r = 0; r < 2; ++r) {                                       \
      const unsigned short* gp = Bm + (size_t)(n0 + r * 64 + rowA) * K + k0_ + kcol;      \
      __builtin_amdgcn_global_load_lds((const __attribute__((address_space(1))) void*)gp, \
          (__attribute__((address_space(3))) void*)&(dB)[r * 2048 + wv * 512], 16, 0, 0); \
    }                                                                                     \
  }

#define GS_COMPUTE(dA, dB)                                                                \
  {                                                                                       \
    bf16x8 afr[4], bfr[4];                                                                \
    _Pragma("unroll") for (int mi = 0; mi < 4; ++mi)                                      \
      afr[mi] = *(const bf16x8*)&(dA)[(wm * 64 + mi * 16 + lane15) * 32 + quad8];         \
    _Pragma("unroll") for (int ni = 0; ni < 4; ++ni)                                      \
      bfr[ni] = *(const bf16x8*)&(dB)[(wn * 64 + ni * 16 + lane15) * 32 + quad8];         \
    _Pragma("unroll") for (int mi = 0; mi < 4; ++mi)                                      \
      _Pragma("unroll") for (int ni = 0; ni < 4; ++ni)                                    \
        acc[mi][ni] =                                                                     \
            __builtin_amdgcn_mfma_f32_16x16x32_bf16(afr[mi], bfr[ni], acc[mi][ni], 0, 0, 0); \
  }

  int kbase = z * KH;
  int nst = KH >> 5;  // even
  GS_STAGE(sA0, sB0, kbase);
  for (int t = 0; t < nst; t += 2) {
    GS_STAGE(sA1, sB1, kbase + (t + 1) * 32);
    asm volatile("s_waitcnt vmcnt(4)" ::: "memory");
    __builtin_amdgcn_s_barrier();
    GS_COMPUTE(sA0, sB0);
    __builtin_amdgcn_s_barrier();
    if (t + 2 < nst) {
      GS_STAGE(sA0, sB0, kbase + (t + 2) * 32);
      asm volatile("s_waitcnt vmcnt(4)" ::: "memory");
    } else {
      asm volatile("s_waitcnt vmcnt(0)" ::: "memory");
    }
    __builtin_amdgcn_s_barrier();
    GS_COMPUTE(sA1, sB1);
    __builtin_amdgcn_s_barrier();
  }
#undef GS_STAGE
#undef GS_COMPUTE

  // vectorized epilogue: LDS-transpose each 32-row chunk, pack 16ch/thread -> 2 uint4 stores
  unsigned short* outH = part + (size_t)z * M * N;
  int trow = tid >> 3;              // 0..31
  int tcol16 = (tid & 7) * 16;      // 0..112
  int growBase = m0 + (trow >> 4) * 64 + (trow & 15);
#pragma unroll
  for (int mi = 0; mi < 4; ++mi) {
    __syncthreads();
#pragma unroll
    for (int ni = 0; ni < 4; ++ni)
#pragma unroll
      for (int reg = 0; reg < 4; ++reg)
        tbuf[(wm * 16 + quad * 4 + reg) * 132 + wn * 64 + ni * 16 + lane15] = acc[mi][ni][reg];
    __syncthreads();
    int gr = growBase + mi * 16;
    const float* lp = &tbuf[trow * 132 + tcol16];
    unsigned o[8];
#pragma unroll
    for (int j = 0; j < 8; ++j)
      o[j] = (unsigned)f2bf(lp[2 * j]) | ((unsigned)f2bf(lp[2 * j + 1]) << 16);
    unsigned short* op = outH + (size_t)gr * 256 + n0 + tcol16;
    *(uint4*)(op) = uint4{o[0], o[1], o[2], o[3]};
    *(uint4*)(op + 8) = uint4{o[4], o[5], o[6], o[7]};
  }
}

// ---------------- epilogue: sum NS bf16 partials, folded BN + ReLU -> bf16 (+opt padded copy) ----------------
template <int NS, int PAD>
__global__ __launch_bounds__(256) void epi_bn(const unsigned short* __restrict__ part,
                                              const float* __restrict__ scale,
                                              const float* __restrict__ shift,
                                              unsigned short* __restrict__ outT,
                                              unsigned short* __restrict__ outP) {
  int gid = blockIdx.x * 256 + threadIdx.x;   // 16384*32
  int row = gid >> 5, c0 = (gid & 31) * 8;
  float v[8] = {};
#pragma unroll
  for (int s = 0; s < NS; ++s) {
    uint4 q = *(const uint4*)(part + (size_t)s * 16384 * 256 + (size_t)row * 256 + c0);
    unsigned u[4] = {q.x, q.y, q.z, q.w};
#pragma unroll
    for (int j = 0; j < 4; ++j) {
      v[2 * j]     += bf2f((unsigned short)(u[j] & 0xffffu));
      v[2 * j + 1] += bf2f((unsigned short)(u[j] >> 16));
    }
  }
  float sc[8], sh[8];
  *(float4*)&sc[0] = *(const float4*)(scale + c0); *(float4*)&sc[4] = *(const float4*)(scale + c0 + 4);
  *(float4*)&sh[0] = *(const float4*)(shift + c0); *(float4*)&sh[4] = *(const float4*)(shift + c0 + 4);
  unsigned o[4];
#pragma unroll
  for (int j = 0; j < 4; ++j) {
    float lo = fmaxf(v[2 * j] * sc[2 * j] + sh[2 * j], 0.f);
    float hi = fmaxf(v[2 * j + 1] * sc[2 * j + 1] + sh[2 * j + 1], 0.f);
    o[j] = (unsigned)f2bf(lo) | ((unsigned)f2bf(hi) << 16);
  }
  uint4 pk{o[0], o[1], o[2], o[3]};
  *(uint4*)(outT + (size_t)row * 256 + c0) = pk;
  if constexpr (PAD) {
    int bb = row >> 12, p = row & 4095;
    *(uint4*)(outP + (((size_t)(bb * 68) + (p >> 6) + 2) * 68 + (p & 63) + 2) * 256 + c0) = pk;
  }
}

// ---------------- final GEMM (1x1 conv #3), BN3 pre-folded, T4 pipeline ----------------
__global__ __launch_bounds__(256) void gemm_res(
    const unsigned short* __restrict__ A, const unsigned short* __restrict__ Bm,
    float* __restrict__ outp, const float* __restrict__ shift3,
    const float* __restrict__ resid, int M, int N, int K, long bStrideB, long bStrideOut) {
  __shared__ __align__(16) char blob[16896];
  __shared__ __align__(16) unsigned short sA1[4096];
  __shared__ __align__(16) unsigned short sB1[4096];
  unsigned short* sA0 = (unsigned short*)blob;
  unsigned short* sB0 = (unsigned short*)(blob + 8192);
  float* tbuf = (float*)blob;
  int tid = threadIdx.x, lane = tid & 63, wv = tid >> 6;
  int z = blockIdx.z;
  const unsigned short* Bz = Bm + (size_t)z * bStrideB;
  int m0 = blockIdx.y * 128, n0 = blockIdx.x * 128;
  f32x4 acc[4][4] = {};
  int rowA = tid >> 2;
  int kcol = (tid & 3) * 8;
  int wm = wv & 1, wn = wv >> 1;
  int lane15 = lane & 15, quad8 = (lane >> 4) * 8, quad = lane >> 4;

#define GR_STAGE(dA, dB, K0)                                                              \
  {                                                                                       \
    int k0_ = (K0);                                                                       \
    _Pragma("unroll") for (int r = 0; r < 2; ++r) {                                       \
      const unsigned short* gp = A + (size_t)(m0 + r * 64 + rowA) * K + k0_ + kcol;       \
      __builtin_amdgcn_global_load_lds((const __attribute__((address_space(1))) void*)gp, \
          (__attribute__((address_space(3))) void*)&(dA)[r * 2048 + wv * 512], 16, 0, 0); \
    }                                                                                     \
    _Pragma("unroll") for (int r = 0; r < 2; ++r) {                                       \
      const unsigned short* gp = Bz + (size_t)(n0 + r * 64 + rowA) * K + k0_ + kcol;      \
      __builtin_amdgcn_global_load_lds((const __attribute__((address_space(1))) void*)gp, \
          (__attribute__((address_space(3))) void*)&(dB)[r * 2048 + wv * 512], 16, 0, 0); \
    }                                                                                     \
  }

#define GR_COMPUTE(dA, dB)                                                                \
  {                                                                                       \
    bf16x8 afr[4], bfr[4];                                                                \
    _Pragma("unroll") for (int mi = 0; mi < 4; ++mi)                                      \
      afr[mi] = *(const bf16x8*)&(dA)[(wm * 64 + mi * 16 + lane15) * 32 + quad8];         \
    _Pragma("unroll") for (int ni = 0; ni < 4; ++ni)                                      \
      bfr[ni] = *(const bf16x8*)&(dB)[(wn * 64 + ni * 16 + lane15) * 32 + quad8];         \
    _Pragma("unroll") for (int mi = 0; mi < 4; ++mi)                                      \
      _Pragma("unroll") for (int ni = 0; ni < 4; ++ni)                                    \
        acc[mi][ni] =                                                                     \
            __builtin_amdgcn_mfma_f32_16x16x32_bf16(afr[mi], bfr[ni], acc[mi][ni], 0, 0, 0); \
  }

  int nst = K >> 5;  // 8: even
  GR_STAGE(sA0, sB0, 0);
  for (int t = 0; t < nst; t += 2) {
    GR_STAGE(sA1, sB1, (t + 1) * 32);
    asm volatile("s_waitcnt vmcnt(4)" ::: "memory");
    __builtin_amdgcn_s_barrier();
    GR_COMPUTE(sA0, sB0);
    __builtin_amdgcn_s_barrier();
    if (t + 2 < nst) {
      GR_STAGE(sA0, sB0, (t + 2) * 32);
      asm volatile("s_waitcnt vmcnt(4)" ::: "memory");
    } else {
      asm volatile("s_waitcnt vmcnt(0)" ::: "memory");
    }
    __builtin_amdgcn_s_barrier();
    GR_COMPUTE(sA1, sB1);
    __builtin_amdgcn_s_barrier();
  }
#undef GR_STAGE
#undef GR_COMPUTE

  float* outF = outp + (size_t)z * bStrideOut;
  const float* res = resid + (size_t)z * bStrideOut;
  int trow = tid >> 3;
  int tcol = (tid & 7) * 4;
  int growBase = m0 + (trow >> 4) * 64 + (trow & 15);
#pragma unroll
  for (int mi = 0; mi < 4; ++mi) {
    __syncthreads();
#pragma unroll
    for (int ni = 0; ni < 4; ++ni)
#pragma unroll
      for (int reg = 0; reg < 4; ++reg)
        tbuf[(wm * 16 + quad * 4 + reg) * 132 + wn * 64 + ni * 16 + lane15] = acc[mi][ni][reg];
    __syncthreads();
    int gr = growBase + mi * 16;
    float sh = shift3[gr];
    const float* rp = res + (size_t)gr * N + n0 + tcol;
    float* op = outF + (size_t)gr * N + n0 + tcol;
    const float* lp = &tbuf[trow * 132 + tcol];
#pragma unroll
    for (int j = 0; j < 4; ++j) {
      float4 rv = *(const float4*)(rp + j * 32);
      float4 lv = *(const float4*)(lp + j * 32);
      float4 ov;
      ov.x = fmaxf(lv.x + sh + rv.x, 0.f);
      ov.y = fmaxf(lv.y + sh + rv.y, 0.f);
      ov.z = fmaxf(lv.z + sh + rv.z, 0.f);
      ov.w = fmaxf(lv.w + sh + rv.w, 0.f);
      *(float4*)(op + j * 32) = ov;
    }
  }
}

// ---------------- offset conv as MFMA GEMM over padded act1P, T4 pipeline ----------------
__global__ __launch_bounds__(256) void off_gemm(const unsigned short* __restrict__ actP,
                                                const unsigned short* __restrict__ wob,
                                                const float* __restrict__ boff,
                                                float* __restrict__ offsP) {
  __shared__ __align__(16) unsigned short sA0[4096];
  __shared__ __align__(16) unsigned short sB0[2048];
  __shared__ __align__(16) unsigned short sA1[4096];
  __shared__ __align__(16) unsigned short sB1[2048];
  int tid = threadIdx.x, lane = tid & 63, wv = tid >> 6;
  int m0 = blockIdx.x * 64;
  int lane15 = lane & 15, quad8 = (lane >> 4) * 8;
  int rowA = tid >> 3;
  int kc = (tid & 7) * 8;

  const unsigned short* baseA[2];
#pragma unroll
  for (int r = 0; r < 2; ++r) {
    int row = m0 + r * 32 + rowA;
    int b = row >> 12, p = row & 4095;
    baseA[r] = actP + (((size_t)(b * 68) + (p >> 6) + 2) * 68 + (p & 63) + 2) * 256 + kc;
  }
  const unsigned short* baseB = wob + (size_t)rowA * 2304 + kc;

  f32x4 acc[2] = {};

#define OG_STAGE(dA, dB, S)                                                               \
  {                                                                                       \
    int s_ = (S); int kk_ = s_ >> 2; int c0_ = (s_ & 3) * 64;                             \
    long shift_ = (long)(((kk_ / 3) * 2 - 2) * 68 + ((kk_ % 3) * 2 - 2));                 \
    _Pragma("unroll") for (int r = 0; r < 2; ++r) {                                       \
      const unsigned short* gp = baseA[r] + shift_ * 256 + c0_;                           \
      __builtin_amdgcn_global_load_lds((const __attribute__((address_space(1))) void*)gp, \
          (__attribute__((address_space(3))) void*)&(dA)[r * 2048 + wv * 512], 16, 0, 0); \
    }                                                                                     \
    {                                                                                     \
      const unsigned short* gp = baseB + kk_ * 256 + c0_;                                 \
      __builtin_amdgcn_global_load_lds((const __attribute__((address_space(1))) void*)gp, \
          (__attribute__((address_space(3))) void*)&(dB)[wv * 512], 16, 0, 0);            \
    }                                                                                     \
  }

#define OG_COMPUTE(dA, dB)                                                                \
  {                                                                                       \
    bf16x8 afr[2], bfr[2][2];                                                             \
    _Pragma("unroll") for (int kq = 0; kq < 2; ++kq) {                                    \
      afr[kq] = *(const bf16x8*)&(dA)[(wv * 16 + lane15) * 64 + kq * 32 + quad8];         \
      _Pragma("unroll") for (int ni = 0; ni < 2; ++ni)                                    \
        bfr[kq][ni] = *(const bf16x8*)&(dB)[(ni * 16 + lane15) * 64 + kq * 32 + quad8];   \
    }                                                                                     \
    _Pragma("unroll") for (int kq = 0; kq < 2; ++kq)                                      \
      _Pragma("unroll") for (int ni = 0; ni < 2; ++ni)                                    \
        acc[ni] = __builtin_amdgcn_mfma_f32_16x16x32_bf16(afr[kq], bfr[kq][ni], acc[ni], 0, 0, 0); \
  }

  OG_STAGE(sA0, sB0, 0);
  for (int s = 0; s < 36; s += 2) {
    OG_STAGE(sA1, sB1, s + 1);
    asm volatile("s_waitcnt vmcnt(3)" ::: "memory");
    __builtin_amdgcn_s_barrier();
    OG_COMPUTE(sA0, sB0);
    __builtin_amdgcn_s_barrier();
    if (s + 2 < 36) {
      OG_STAGE(sA0, sB0, s + 2);
      asm volatile("s_waitcnt vmcnt(3)" ::: "memory");
    } else {
      asm volatile("s_waitcnt vmcnt(0)" ::: "memory");
    }
    __builtin_amdgcn_s_barrier();
    OG_COMPUTE(sA1, sB1);
    __builtin_amdgcn_s_barrier();
  }
#undef OG_STAGE
#undef OG_COMPUTE

#pragma unroll
  for (int ni = 0; ni < 2; ++ni) {
    int o = ni * 16 + lane15;
    if (o < 18) {
      float bo = boff[o];
#pragma unroll
      for (int reg = 0; reg < 4; ++reg) {
        int row = m0 + wv * 16 + (lane >> 4) * 4 + reg;
        offsP[(size_t)row * 18 + o] = acc[ni][reg] + bo;
      }
    }
  }
}

// ---------------- fused deform-sample + GEMM2: A-tiles generated by bilinear sampling ----------------
// z in {0,1,2}: kk range [3z, 3z+3), 24 K-steps of 32ch. Per step: 8 corner uint4 loads
// (reg-staged) + 2 B global_load_lds; counted vmcnt: 10 = wait prev B, 2 = wait corners.
// Invalid corners: clamped address + zero weight (== deform_sample's zeroed-value path).
struct Geom { float w00, w01, w10, w11; int b00, b01, b10, b11; };

__device__ __forceinline__ Geom make_geom(const float* __restrict__ offs, int row, int h, int w, int kk) {
  float offy = offs[(size_t)row * 18 + 2 * kk];
  float offx = offs[(size_t)row * 18 + 2 * kk + 1];
  float py = (float)(h + (kk / 3) * 2 - 2) + offy;
  float px = (float)(w + (kk % 3) * 2 - 2) + offx;
  float fy = floorf(py), fx = floorf(px);
  int y0 = (int)fy, x0 = (int)fx;
  float wy = py - fy, wx = px - fx;
  bool yv0 = (y0 >= 0 && y0 < 64), yv1 = (y0 >= -1 && y0 < 63);
  bool xv0 = (x0 >= 0 && x0 < 64), xv1 = (x0 >= -1 && x0 < 63);
  Geom g;
  g.w00 = (yv0 && xv0) ? (1.f - wy) * (1.f - wx) : 0.f;
  g.w01 = (yv0 && xv1) ? (1.f - wy) * wx : 0.f;
  g.w10 = (yv1 && xv0) ? wy * (1.f - wx) : 0.f;
  g.w11 = (yv1 && xv1) ? wy * wx : 0.f;
  int y0c = min(max(y0, 0), 63), y1c = min(max(y0 + 1, 0), 63);
  int x0c = min(max(x0, 0), 63), x1c = min(max(x0 + 1, 0), 63);
  g.b00 = (y0c * 64 + x0c) * 256; g.b01 = (y0c * 64 + x1c) * 256;
  g.b10 = (y1c * 64 + x0c) * 256; g.b11 = (y1c * 64 + x1c) * 256;
  return g;
}

__global__ __launch_bounds__(256, 3) void gemm_deform(
    const unsigned short* __restrict__ act1T, const float* __restrict__ offs,
    const unsigned short* __restrict__ Bm, unsigned short* __restrict__ part) {
  __shared__ __align__(16) char blob[16896];              // sA0|sB0; tbuf aliases
  __shared__ __align__(16) unsigned short sA1[4096];
  __shared__ __align__(16) unsigned short sB1[4096];
  unsigned short* sA0 = (unsigned short*)blob;
  unsigned short* sB0 = (unsigned short*)(blob + 8192);
  float* tbuf = (float*)blob;
  int tid = threadIdx.x, lane = tid & 63, wv = tid >> 6;
  int z = blockIdx.z;
  int m0 = blockIdx.y * 128, n0 = blockIdx.x * 128;
  f32x4 acc[4][4] = {};
  // B staging mapping
  int rowB = tid >> 2, kcolB = (tid & 3) * 8;
  // A sampling mapping: 2 threads/row, 16 ch each
  int rowl = tid >> 1, halfc = tid & 1;
  int row = m0 + rowl;
  int b = row >> 12, p = row & 4095, h = p >> 6, w = p & 63;
  const unsigned short* actb = act1T + (size_t)b * 1048576 + halfc * 16;
  int wm = wv & 1, wn = wv >> 1;
  int lane15 = lane & 15, quad8 = (lane >> 4) * 8, quad = lane >> 4;

  Geom g0 = make_geom(offs, row, h, w, 3 * z + 0);
  Geom g1 = make_geom(offs, row, h, w, 3 * z + 1);
  Geom g2 = make_geom(offs, row, h, w, 3 * z + 2);

  uint4 rc0, rc1, rc2, rc3, rc4, rc5, rc6, rc7;

#define DF_ISSUE_A(G, CS)                                                                 \
  {                                                                                       \
    const unsigned short* pa = actb + (CS) * 32;                                          \
    rc0 = *(const uint4*)(pa + (G).b00); rc1 = *(const uint4*)(pa + (G).b00 + 8);         \
    rc2 = *(const uint4*)(pa + (G).b01); rc3 = *(const uint4*)(pa + (G).b01 + 8);         \
    rc4 = *(const uint4*)(pa + (G).b10); rc5 = *(const uint4*)(pa + (G).b10 + 8);         \
    rc6 = *(const uint4*)(pa + (G).b11); rc7 = *(const uint4*)(pa + (G).b11 + 8);         \
  }

#define DF_ISSUE_B(DB, BCOL)                                                              \
  {                                                                                       \
    _Pragma("unroll") for (int r = 0; r < 2; ++r) {                                       \
      const unsigned short* gp = Bm + (size_t)(n0 + r * 64 + rowB) * 2304 + (BCOL) + kcolB; \
      __builtin_amdgcn_global_load_lds((const __attribute__((address_space(1))) void*)gp, \
          (__attribute__((address_space(3))) void*)&(DB)[r * 2048 + wv * 512], 16, 0, 0); \
    }                                                                                     \
  }

#define DF_LERP_WRITE(G, DA)                                                              \
  {                                                                                       \
    unsigned u00[8] = {rc0.x, rc0.y, rc0.z, rc0.w, rc1.x, rc1.y, rc1.z, rc1.w};           \
    unsigned u01[8] = {rc2.x, rc2.y, rc2.z, rc2.w, rc3.x, rc3.y, rc3.z, rc3.w};           \
    unsigned u10[8] = {rc4.x, rc4.y, rc4.z, rc4.w, rc5.x, rc5.y, rc5.z, rc5.w};           \
    unsigned u11[8] = {rc6.x, rc6.y, rc6.z, rc6.w, rc7.x, rc7.y, rc7.z, rc7.w};           \
    unsigned o8[8];                                                                       \
    _Pragma("unroll") for (int j = 0; j < 8; ++j) {                                       \
      float lo = bf2f((unsigned short)(u00[j] & 0xffffu)) * (G).w00 +                     \
                 bf2f((unsigned short)(u01[j] & 0xffffu)) * (G).w01 +                     \
                 bf2f((unsigned short)(u10[j] & 0xffffu)) * (G).w10 +                     \
                 bf2f((unsigned short)(u11[j] & 0xffffu)) * (G).w11;                      \
      float hi = bf2f((unsigned short)(u00[j] >> 16)) * (G).w00 +                         \
                 bf2f((unsigned short)(u01[j] >> 16)) * (G).w01 +                         \
                 bf2f((unsigned short)(u10[j] >> 16)) * (G).w10 +                         \
                 bf2f((unsigned short)(u11[j] >> 16)) * (G).w11;                          \
      o8[j] = (unsigned)f2bf(lo) | ((unsigned)f2bf(hi) << 16);                            \
    }                                                                                     \
    unsigned short* wp = (DA) + rowl * 32 + halfc * 16;                                   \
    *(uint4*)(wp) = uint4{o8[0], o8[1], o8[2], o8[3]};                                    \
    *(uint4*)(wp + 8) = uint4{o8[4], o8[5], o8[6], o8[7]};                                \
  }

#define DF_COMPUTE(DA, DB)                                                                \
  {                                                                                       \
    bf16x8 afr[4], bfr[4];                                                                \
    _Pragma("unroll") for (int mi = 0; mi < 4; ++mi)                                      \
      afr[mi] = *(const bf16x8*)&(DA)[(wm * 64 + mi * 16 + lane15) * 32 + quad8];         \
    _Pragma("unroll") for (int ni = 0; ni < 4; ++ni)                                      \
      bfr[ni] = *(const bf16x8*)&(DB)[(wn * 64 + ni * 16 + lane15) * 32 + quad8];         \
    _Pragma("unroll") for (int mi = 0; mi < 4; ++mi)                                      \
      _Pragma("unroll") for (int ni = 0; ni < 4; ++ni)                                    \
        acc[mi][ni] =                                                                     \
            __builtin_amdgcn_mfma_f32_16x16x32_bf16(afr[mi], bfr[ni], acc[mi][ni], 0, 0, 0); \
  }

#define DF_BC(J, CS) ((3 * z + (J)) * 256 + (CS) * 32)

#define DF_BODY(GN, CSN, BCN, AC, BMC, AN, BMN)                                           \
  {                                                                                       \
    DF_ISSUE_A(GN, CSN);                                                                  \
    DF_ISSUE_B(BMN, BCN);                                                                 \
    asm volatile("s_waitcnt vmcnt(10)" ::: "memory");                                     \
    asm volatile("s_waitcnt lgkmcnt(0)" ::: "memory");                                    \
    __builtin_amdgcn_s_barrier();                                                         \
    DF_COMPUTE(AC, BMC);                                                                  \
    asm volatile("s_waitcnt vmcnt(2)" ::: "memory");                                      \
    DF_LERP_WRITE(GN, AN);                                                                \
    __builtin_amdgcn_s_barrier();                                                         \
  }

  // prologue: stage step 0
  DF_ISSUE_A(g0, 0);
  DF_ISSUE_B(sB0, DF_BC(0, 0));
  asm volatile("s_waitcnt vmcnt(2)" ::: "memory");
  DF_LERP_WRITE(g0, sA0);

  // section 0 (kk = 3z): steps 0..7
  for (int cs = 0; cs < 6; cs += 2) {
    DF_BODY(g0, cs + 1, DF_BC(0, cs + 1), sA0, sB0, sA1, sB1);
    DF_BODY(g0, cs + 2, DF_BC(0, cs + 2), sA1, sB1, sA0, sB0);
  }
  DF_BODY(g0, 7, DF_BC(0, 7), sA0, sB0, sA1, sB1);
  DF_BODY(g1, 0, DF_BC(1, 0), sA1, sB1, sA0, sB0);
  // section 1 (kk = 3z+1): steps 8..15
  for (int cs = 0; cs < 6; cs += 2) {
    DF_BODY(g1, cs + 1, DF_BC(1, cs + 1), sA0, sB0, sA1, sB1);
    DF_BODY(g1, cs + 2, DF_BC(1, cs + 2), sA1, sB1, sA0, sB0);
  }
  DF_BODY(g1, 7, DF_BC(1, 7), sA0, sB0, sA1, sB1);
  DF_BODY(g2, 0, DF_BC(2, 0), sA1, sB1, sA0, sB0);
  // section 2 (kk = 3z+2): steps 16..23
  for (int cs = 0; cs < 6; cs += 2) {
    DF_BODY(g2, cs + 1, DF_BC(2, cs + 1), sA0, sB0, sA1, sB1);
    DF_BODY(g2, cs + 2, DF_BC(2, cs + 2), sA1, sB1, sA0, sB0);
  }
  DF_BODY(g2, 7, DF_BC(2, 7), sA0, sB0, sA1, sB1);
  // last step 23: compute only
  asm volatile("s_waitcnt vmcnt(0)" ::: "memory");
  asm volatile("s_waitcnt lgkmcnt(0)" ::: "memory");
  __builtin_amdgcn_s_barrier();
  DF_COMPUTE(sA1, sB1);
  __builtin_amdgcn_s_barrier();

#undef DF_ISSUE_A
#undef DF_ISSUE_B
#undef DF_LERP_WRITE
#undef DF_COMPUTE
#undef DF_BC
#undef DF_BODY

  // epilogue: LDS-transpose, pack 16ch/thread -> 2 uint4 stores into z-partial
  unsigned short* outH = part + (size_t)z * 16384 * 256;
  int trow = tid >> 3;
  int tcol16 = (tid & 7) * 16;
  int growBase = m0 + (trow >> 4) * 64 + (trow & 15);
#pragma unroll
  for (int mi = 0; mi < 4; ++mi) {
    __syncthreads();
#pragma unroll
    for (int ni = 0; ni < 4; ++ni)
#pragma unroll
      for (int reg = 0; reg < 4; ++reg)
        tbuf[(wm * 16 + quad * 4 + reg) * 132 + wn * 64 + ni * 16 + lane15] = acc[mi][ni][reg];
    __syncthreads();
    int gr = growBase + mi * 16;
    const float* lp = &tbuf[trow * 132 + tcol16];
    unsigned o[8];
#pragma unroll
    for (int j = 0; j < 8; ++j)
      o[j] = (unsigned)f2bf(lp[2 * j]) | ((unsigned)f2bf(lp[2 * j + 1]) << 16);
    unsigned short* op = outH + (size_t)gr * 256 + n0 + tcol16;
    *(uint4*)(op) = uint4{o[0], o[1], o[2], o[3]};
    *(uint4*)(op + 8) = uint4{o[4], o[5], o[6], o[7]};
  }
}

extern "C" void kernel_launch(void* const* d_in, const int* in_sizes, int n_in,
                              void* d_out, int out_size, void* d_ws, size_t ws_size,
                              hipStream_t stream) {
  const float* x      = (const float*)d_in[0];
  const float* w1     = (const float*)d_in[1];
  const float* gamma1 = (const float*)d_in[2];
  const float* beta1  = (const float*)d_in[3];
  const float* mean1  = (const float*)d_in[4];
  const float* var1   = (const float*)d_in[5];
  const float* woff   = (const float*)d_in[6];
  const float* boff   = (const float*)d_in[7];
  const float* w2     = (const float*)d_in[8];
  const float* bconv2 = (const float*)d_in[9];
  const float* gamma2 = (const float*)d_in[10];
  const float* beta2  = (const float*)d_in[11];
  const float* mean2  = (const float*)d_in[12];
  const float* var2   = (const float*)d_in[13];
  const float* w3     = (const float*)d_in[14];
  const float* gamma3 = (const float*)d_in[15];
  const float* beta3  = (const float*)d_in[16];
  const float* mean3  = (const float*)d_in[17];
  const float* var3   = (const float*)d_in[18];

  char* ws = (char*)d_ws;
  unsigned short* xT    = (unsigned short*)(ws);                 // [0, 33.55 MB)
  unsigned short* act1T = (unsigned short*)(ws + 33554432);      //  8,388,608
  unsigned short* act2T = (unsigned short*)(ws + 41943040);      //  8,388,608
  // region [50331648, 125829120) previously S; now act1P + part1
  float*          offs  = (float*)(ws + 125829120);              //  1,179,648
  unsigned short* w1b   = (unsigned short*)(ws + 127008768);     //    524,288
  unsigned short* w2r   = (unsigned short*)(ws + 127533056);     //  1,179,648
  unsigned short* w3b   = (unsigned short*)(ws + 128712704);     //    524,288
  float*          bnS1  = (float*)(ws + 129236992);              //      1,024
  float*          bnH1  = (float*)(ws + 129238016);              //      1,024
  float*          bnS2  = (float*)(ws + 129239040);              //      1,024
  float*          bnH2  = (float*)(ws + 129240064);              //      1,024
  float*          shift3= (float*)(ws + 129241088);              //      4,096
  // aliased (non-overlapping lifetimes):
  unsigned short* act1P = (unsigned short*)(ws + 50331648);   // 9.47 MB padded act1
  unsigned short* part1 = (unsigned short*)(ws + 62914560);   // 2x8 MB bf16
  unsigned short* part2 = (unsigned short*)ws;                // 3x8 MB bf16 = 25.2 MB, xT region (dead post-GEMM1)
  unsigned short* wob   = act2T;                              // 147 KB; dead before epi_bn2 writes act2T

  prep_all<<<6957, 256, 0, stream>>>(w1, w2, woff, w3,
                                     gamma1, beta1, mean1, var1,
                                     gamma2, beta2, mean2, var2, bconv2,
                                     gamma3, beta3, mean3, var3,
                                     w1b, w2r, (uint4*)act1P, wob, w3b, shift3,
                                     bnS1, bnH1, bnS2, bnH2);
  transpose_x<<<dim3(128, 32, 4), 256, 0, stream>>>(x, xT);

  // GEMM1 (K=1024) split x2 -> bf16 partials -> BN1+ReLU epilogue (act1T + padded act1P)
  gemm_split<<<dim3(2, 128, 2), 256, 0, stream>>>(xT, w1b, part1, 16384, 256, 1024, 512);
  epi_bn<2, 1><<<2048, 256, 0, stream>>>(part1, bnS1, bnH1, act1T, act1P);

  off_gemm<<<256, 256, 0, stream>>>(act1P, wob, boff, offs);

  // fused deform-sample + GEMM2 (kk-split z=3) -> bf16 partials -> bias+BN2+ReLU epilogue
  gemm_deform<<<dim3(2, 128, 3), 256, 0, stream>>>(act1T, offs, w2r, part2);
  epi_bn<3, 0><<<2048, 256, 0, stream>>>(part2, bnS2, bnH2, act2T, nullptr);

  // GEMM3: out = relu(w3s @ act2T^T + shift3 + x)
  gemm_res<<<dim3(32, 8, 4), 256, 0, stream>>>(w3b, act2T, (float*)d_out, shift3, x,
                                               1024, 4096, 256, 4096L * 256, 4194304L);
}

// Round 4
// 280.541 us; speedup vs baseline: 1.0856x; 1.0856x over previous
//
#include <hip/hip_runtime.h>

#define EPS_BN 1e-5f

typedef __bf16 bf16x8 __attribute__((ext_vector_type(8)));
typedef float f32x4 __attribute__((ext_vector_type(4)));

__device__ __forceinline__ unsigned short f2bf(float f) {
  union { float f; unsigned u; } v; v.f = f;
  unsigned r = v.u + 0x7fffu + ((v.u >> 16) & 1u);
  return (unsigned short)(r >> 16);
}
__device__ __forceinline__ float bf2f(unsigned short h) {
  union { unsigned u; float f; } v; v.u = ((unsigned)h) << 16;
  return v.f;
}

// ---------------- fused prep ----------------
__global__ __launch_bounds__(256) void prep_all(
    const float* __restrict__ w1, const float* __restrict__ w2, const float* __restrict__ woff,
    const float* __restrict__ w3,
    const float* g1, const float* b1, const float* m1, const float* v1,
    const float* g2, const float* b2, const float* m2, const float* v2, const float* bconv2,
    const float* g3, const float* b3, const float* m3, const float* v3,
    unsigned short* __restrict__ w1b, unsigned short* __restrict__ w2r,
    uint4* __restrict__ act1Pz, unsigned short* __restrict__ wob,
    unsigned short* __restrict__ w3b, float* __restrict__ shift3,
    float* s1, float* h1, float* s2, float* h2) {
  int bid = blockIdx.x, tid = threadIdx.x;
  if (bid < 1024) {
    int i = bid * 256 + tid;
    w1b[i] = f2bf(w1[i]);
  } else if (bid < 3328) {
    int i = (bid - 1024) * 256 + tid;
    int o = i / 2304, r = i % 2304;
    int kk = r / 256, c = r % 256;
    w2r[i] = f2bf(w2[(size_t)o * 2304 + c * 9 + kk]);
  } else if (bid < 5640) {
    int i = (bid - 3328) * 256 + tid;
    if (i < 591872) act1Pz[i] = uint4{0, 0, 0, 0};
  } else if (bid < 5928) {
    int i = (bid - 5640) * 256 + tid;
    int o = i / 2304, r = i % 2304;
    int kk = r / 256, c = r % 256;
    wob[i] = (o < 18) ? f2bf(woff[(size_t)o * 2304 + c * 9 + kk]) : (unsigned short)0;
  } else if (bid < 6952) {
    int i = (bid - 5928) * 256 + tid;
    int o = i >> 8;
    float sc = rsqrtf(v3[o] + EPS_BN) * g3[o];
    w3b[i] = f2bf(w3[i] * sc);
  } else if (bid < 6956) {
    int c = (bid - 6952) * 256 + tid;
    float sc = rsqrtf(v3[c] + EPS_BN) * g3[c];
    shift3[c] = b3[c] - m3[c] * sc;
  } else {
    int c = tid;
    float sc1 = rsqrtf(v1[c] + EPS_BN) * g1[c];
    s1[c] = sc1; h1[c] = b1[c] - m1[c] * sc1;
    float sc2 = rsqrtf(v2[c] + EPS_BN) * g2[c];
    s2[c] = sc2; h2[c] = b2[c] + (bconv2[c] - m2[c]) * sc2;
  }
}

// ---------------- GEMM1 with fused x-transpose: A staged from f32 x (c-major) ----------------
// A-tile 128px x 32c: thread = (px = tid&127, c16 = (tid>>7)*16). 16 scalar f32 loads
// (each coalesced: 64 lanes x 4B consecutive), cvt to bf16, 2x ds_write_b128 into
// [px][32c] LDS (same layout/frag mapping as gemm_split). B via global_load_lds.
// Counted vmcnt: per step pending = 16 A-reg loads + 2 B-DMAs; vmcnt(18)=wait prev B,
// vmcnt(2)=wait this step's A; vmcnt(0) only at tail.
__global__ __launch_bounds__(256) void gemm1_x(
    const float* __restrict__ x, const unsigned short* __restrict__ Bm,
    unsigned short* __restrict__ part, int KH) {
  __shared__ __align__(16) char blob[16896];              // sA0|sB0, tbuf aliases
  __shared__ __align__(16) unsigned short sA1[4096];
  __shared__ __align__(16) unsigned short sB1[4096];
  unsigned short* sA0 = (unsigned short*)blob;
  unsigned short* sB0 = (unsigned short*)(blob + 8192);
  float* tbuf = (float*)blob;                             // epilogue only
  int tid = threadIdx.x, lane = tid & 63, wv = tid >> 6;
  int z = blockIdx.z;
  int m0 = blockIdx.y * 128, n0 = blockIdx.x * 128;
  f32x4 acc[4][4] = {};
  // B staging mapping
  int rowB = tid >> 2, kcolB = (tid & 3) * 8;
  // A staging mapping
  int px = tid & 127, c16 = (tid >> 7) * 16;
  int bb = m0 >> 12, p0 = m0 & 4095;
  const float* xa = x + (size_t)bb * 4194304 + (size_t)c16 * 4096 + (p0 + px);
  int wm = wv & 1, wn = wv >> 1;
  int lane15 = lane & 15, quad8 = (lane >> 4) * 8, quad = lane >> 4;

  float va[16];

#define G1_ISSUE_A(K0)                                                                    \
  {                                                                                       \
    const float* xp = xa + (size_t)(K0) * 4096;                                           \
    _Pragma("unroll") for (int j = 0; j < 16; ++j) va[j] = xp[(size_t)j * 4096];          \
  }

#define G1_ISSUE_B(DB, K0)                                                                \
  {                                                                                       \
    _Pragma("unroll") for (int r = 0; r < 2; ++r) {                                       \
      const unsigned short* gp = Bm + (size_t)(n0 + r * 64 + rowB) * 1024 + (K0) + kcolB; \
      __builtin_amdgcn_global_load_lds((const __attribute__((address_space(1))) void*)gp, \
          (__attribute__((address_space(3))) void*)&(DB)[r * 2048 + wv * 512], 16, 0, 0); \
    }                                                                                     \
  }

#define G1_CVT_WRITE(DA)                                                                  \
  {                                                                                       \
    unsigned o8[8];                                                                       \
    _Pragma("unroll") for (int j = 0; j < 8; ++j)                                         \
      o8[j] = (unsigned)f2bf(va[2 * j]) | ((unsigned)f2bf(va[2 * j + 1]) << 16);          \
    unsigned short* wp = (DA) + px * 32 + c16;                                            \
    *(uint4*)(wp) = uint4{o8[0], o8[1], o8[2], o8[3]};                                    \
    *(uint4*)(wp + 8) = uint4{o8[4], o8[5], o8[6], o8[7]};                                \
  }

#define G1_COMPUTE(DA, DB)                                                                \
  {                                                                                       \
    bf16x8 afr[4], bfr[4];                                                                \
    _Pragma("unroll") for (int mi = 0; mi < 4; ++mi)                                      \
      afr[mi] = *(const bf16x8*)&(DA)[(wm * 64 + mi * 16 + lane15) * 32 + quad8];         \
    _Pragma("unroll") for (int ni = 0; ni < 4; ++ni)                                      \
      bfr[ni] = *(const bf16x8*)&(DB)[(wn * 64 + ni * 16 + lane15) * 32 + quad8];         \
    _Pragma("unroll") for (int mi = 0; mi < 4; ++mi)                                      \
      _Pragma("unroll") for (int ni = 0; ni < 4; ++ni)                                    \
        acc[mi][ni] =                                                                     \
            __builtin_amdgcn_mfma_f32_16x16x32_bf16(afr[mi], bfr[ni], acc[mi][ni], 0, 0, 0); \
  }

#define G1_BODY(K0, AC, BC, AN, BN_)                                                      \
  {                                                                                       \
    G1_ISSUE_A(K0);                                                                       \
    G1_ISSUE_B(BN_, K0);                                                                  \
    asm volatile("s_waitcnt vmcnt(18)" ::: "memory");                                     \
    asm volatile("s_waitcnt lgkmcnt(0)" ::: "memory");                                    \
    __builtin_amdgcn_s_barrier();                                                         \
    G1_COMPUTE(AC, BC);                                                                   \
    asm volatile("s_waitcnt vmcnt(2)" ::: "memory");                                      \
    G1_CVT_WRITE(AN);                                                                     \
    __builtin_amdgcn_s_barrier();                                                         \
  }

  int kbase = z * KH;
  int nst = KH >> 5;  // 16: even
  // prologue: stage step 0 into sA0/sB0
  G1_ISSUE_A(kbase);
  G1_ISSUE_B(sB0, kbase);
  asm volatile("s_waitcnt vmcnt(2)" ::: "memory");
  G1_CVT_WRITE(sA0);
  for (int t = 0; t + 2 < nst; t += 2) {
    G1_BODY(kbase + (t + 1) * 32, sA0, sB0, sA1, sB1);
    G1_BODY(kbase + (t + 2) * 32, sA1, sB1, sA0, sB0);
  }
  G1_BODY(kbase + (nst - 1) * 32, sA0, sB0, sA1, sB1);
  asm volatile("s_waitcnt vmcnt(0)" ::: "memory");
  asm volatile("s_waitcnt lgkmcnt(0)" ::: "memory");
  __builtin_amdgcn_s_barrier();
  G1_COMPUTE(sA1, sB1);
#undef G1_ISSUE_A
#undef G1_ISSUE_B
#undef G1_CVT_WRITE
#undef G1_COMPUTE
#undef G1_BODY

  // vectorized epilogue -> z-partial
  unsigned short* outH = part + (size_t)z * 16384 * 256;
  int trow = tid >> 3;
  int tcol16 = (tid & 7) * 16;
  int growBase = m0 + (trow >> 4) * 64 + (trow & 15);
#pragma unroll
  for (int mi = 0; mi < 4; ++mi) {
    __syncthreads();
#pragma unroll
    for (int ni = 0; ni < 4; ++ni)
#pragma unroll
      for (int reg = 0; reg < 4; ++reg)
        tbuf[(wm * 16 + quad * 4 + reg) * 132 + wn * 64 + ni * 16 + lane15] = acc[mi][ni][reg];
    __syncthreads();
    int gr = growBase + mi * 16;
    const float* lp = &tbuf[trow * 132 + tcol16];
    unsigned o[8];
#pragma unroll
    for (int j = 0; j < 8; ++j)
      o[j] = (unsigned)f2bf(lp[2 * j]) | ((unsigned)f2bf(lp[2 * j + 1]) << 16);
    unsigned short* op = outH + (size_t)gr * 256 + n0 + tcol16;
    *(uint4*)(op) = uint4{o[0], o[1], o[2], o[3]};
    *(uint4*)(op + 8) = uint4{o[4], o[5], o[6], o[7]};
  }
}

// ---------------- K-split MFMA GEMM -> bf16 partials (T4 counted-vmcnt pipeline) ----------------
__global__ __launch_bounds__(256) void gemm_split(
    const unsigned short* __restrict__ A, const unsigned short* __restrict__ Bm,
    unsigned short* __restrict__ part, int M, int N, int K, int KH) {
  __shared__ __align__(16) char blob[16896];              // sA0|sB0, tbuf aliases
  __shared__ __align__(16) unsigned short sA1[4096];
  __shared__ __align__(16) unsigned short sB1[4096];
  unsigned short* sA0 = (unsigned short*)blob;
  unsigned short* sB0 = (unsigned short*)(blob + 8192);
  float* tbuf = (float*)blob;                             // epilogue only
  int tid = threadIdx.x, lane = tid & 63, wv = tid >> 6;
  int z = blockIdx.z;
  int m0 = blockIdx.y * 128, n0 = blockIdx.x * 128;
  f32x4 acc[4][4] = {};
  int rowA = tid >> 2;
  int kcol = (tid & 3) * 8;
  int wm = wv & 1, wn = wv >> 1;
  int lane15 = lane & 15, quad8 = (lane >> 4) * 8, quad = lane >> 4;

#define GS_STAGE(dA, dB, K0)                                                              \
  {                                                                                       \
    int k0_ = (K0);                                                                       \
    _Pragma("unroll") for (int r = 0; r < 2; ++r) {                                       \
      const unsigned short* gp = A + (size_t)(m0 + r * 64 + rowA) * K + k0_ + kcol;       \
      __builtin_amdgcn_global_load_lds((const __attribute__((address_space(1))) void*)gp, \
          (__attribute__((address_space(3))) void*)&(dA)[r * 2048 + wv * 512], 16, 0, 0); \
    }                                                                                     \
    _Pragma("unroll") for (int r = 0; r < 2; ++r) {                                       \
      const unsigned short* gp = Bm + (size_t)(n0 + r * 64 + rowA) * K + k0_ + kcol;      \
      __builtin_amdgcn_global_load_lds((const __attribute__((address_space(1))) void*)gp, \
          (__attribute__((address_space(3))) void*)&(dB)[r * 2048 + wv * 512], 16, 0, 0); \
    }                                                                                     \
  }

#define GS_COMPUTE(dA, dB)                                                                \
  {                                                                                       \
    bf16x8 afr[4], bfr[4];                                                                \
    _Pragma("unroll") for (int mi = 0; mi < 4; ++mi)                                      \
      afr[mi] = *(const bf16x8*)&(dA)[(wm * 64 + mi * 16 + lane15) * 32 + quad8];         \
    _Pragma("unroll") for (int ni = 0; ni < 4; ++ni)                                      \
      bfr[ni] = *(const bf16x8*)&(dB)[(wn * 64 + ni * 16 + lane15) * 32 + quad8];         \
    _Pragma("unroll") for (int mi = 0; mi < 4; ++mi)                                      \
      _Pragma("unroll") for (int ni = 0; ni < 4; ++ni)                                    \
        acc[mi][ni] =                                                                     \
            __builtin_amdgcn_mfma_f32_16x16x32_bf16(afr[mi], bfr[ni], acc[mi][ni], 0, 0, 0); \
  }

  int kbase = z * KH;
  int nst = KH >> 5;  // even
  GS_STAGE(sA0, sB0, kbase);
  for (int t = 0; t < nst; t += 2) {
    GS_STAGE(sA1, sB1, kbase + (t + 1) * 32);
    asm volatile("s_waitcnt vmcnt(4)" ::: "memory");
    __builtin_amdgcn_s_barrier();
    GS_COMPUTE(sA0, sB0);
    __builtin_amdgcn_s_barrier();
    if (t + 2 < nst) {
      GS_STAGE(sA0, sB0, kbase + (t + 2) * 32);
      asm volatile("s_waitcnt vmcnt(4)" ::: "memory");
    } else {
      asm volatile("s_waitcnt vmcnt(0)" ::: "memory");
    }
    __builtin_amdgcn_s_barrier();
    GS_COMPUTE(sA1, sB1);
    __builtin_amdgcn_s_barrier();
  }
#undef GS_STAGE
#undef GS_COMPUTE

  // vectorized epilogue: LDS-transpose each 32-row chunk, pack 16ch/thread -> 2 uint4 stores
  unsigned short* outH = part + (size_t)z * M * N;
  int trow = tid >> 3;              // 0..31
  int tcol16 = (tid & 7) * 16;      // 0..112
  int growBase = m0 + (trow >> 4) * 64 + (trow & 15);
#pragma unroll
  for (int mi = 0; mi < 4; ++mi) {
    __syncthreads();
#pragma unroll
    for (int ni = 0; ni < 4; ++ni)
#pragma unroll
      for (int reg = 0; reg < 4; ++reg)
        tbuf[(wm * 16 + quad * 4 + reg) * 132 + wn * 64 + ni * 16 + lane15] = acc[mi][ni][reg];
    __syncthreads();
    int gr = growBase + mi * 16;
    const float* lp = &tbuf[trow * 132 + tcol16];
    unsigned o[8];
#pragma unroll
    for (int j = 0; j < 8; ++j)
      o[j] = (unsigned)f2bf(lp[2 * j]) | ((unsigned)f2bf(lp[2 * j + 1]) << 16);
    unsigned short* op = outH + (size_t)gr * 256 + n0 + tcol16;
    *(uint4*)(op) = uint4{o[0], o[1], o[2], o[3]};
    *(uint4*)(op + 8) = uint4{o[4], o[5], o[6], o[7]};
  }
}

// ---------------- epilogue: sum NS bf16 partials, folded BN + ReLU -> bf16 (+opt padded copy) ----------------
template <int NS, int PAD>
__global__ __launch_bounds__(256) void epi_bn(const unsigned short* __restrict__ part,
                                              const float* __restrict__ scale,
                                              const float* __restrict__ shift,
                                              unsigned short* __restrict__ outT,
                                              unsigned short* __restrict__ outP) {
  int gid = blockIdx.x * 256 + threadIdx.x;   // 16384*32
  int row = gid >> 5, c0 = (gid & 31) * 8;
  float v[8] = {};
#pragma unroll
  for (int s = 0; s < NS; ++s) {
    uint4 q = *(const uint4*)(part + (size_t)s * 16384 * 256 + (size_t)row * 256 + c0);
    unsigned u[4] = {q.x, q.y, q.z, q.w};
#pragma unroll
    for (int j = 0; j < 4; ++j) {
      v[2 * j]     += bf2f((unsigned short)(u[j] & 0xffffu));
      v[2 * j + 1] += bf2f((unsigned short)(u[j] >> 16));
    }
  }
  float sc[8], sh[8];
  *(float4*)&sc[0] = *(const float4*)(scale + c0); *(float4*)&sc[4] = *(const float4*)(scale + c0 + 4);
  *(float4*)&sh[0] = *(const float4*)(shift + c0); *(float4*)&sh[4] = *(const float4*)(shift + c0 + 4);
  unsigned o[4];
#pragma unroll
  for (int j = 0; j < 4; ++j) {
    float lo = fmaxf(v[2 * j] * sc[2 * j] + sh[2 * j], 0.f);
    float hi = fmaxf(v[2 * j + 1] * sc[2 * j + 1] + sh[2 * j + 1], 0.f);
    o[j] = (unsigned)f2bf(lo) | ((unsigned)f2bf(hi) << 16);
  }
  uint4 pk{o[0], o[1], o[2], o[3]};
  *(uint4*)(outT + (size_t)row * 256 + c0) = pk;
  if constexpr (PAD) {
    int bb = row >> 12, p = row & 4095;
    *(uint4*)(outP + (((size_t)(bb * 68) + (p >> 6) + 2) * 68 + (p & 63) + 2) * 256 + c0) = pk;
  }
}

// ---------------- final GEMM (1x1 conv #3), BN3 pre-folded, T4 pipeline ----------------
__global__ __launch_bounds__(256) void gemm_res(
    const unsigned short* __restrict__ A, const unsigned short* __restrict__ Bm,
    float* __restrict__ outp, const float* __restrict__ shift3,
    const float* __restrict__ resid, int M, int N, int K, long bStrideB, long bStrideOut) {
  __shared__ __align__(16) char blob[16896];
  __shared__ __align__(16) unsigned short sA1[4096];
  __shared__ __align__(16) unsigned short sB1[4096];
  unsigned short* sA0 = (unsigned short*)blob;
  unsigned short* sB0 = (unsigned short*)(blob + 8192);
  float* tbuf = (float*)blob;
  int tid = threadIdx.x, lane = tid & 63, wv = tid >> 6;
  int z = blockIdx.z;
  const unsigned short* Bz = Bm + (size_t)z * bStrideB;
  int m0 = blockIdx.y * 128, n0 = blockIdx.x * 128;
  f32x4 acc[4][4] = {};
  int rowA = tid >> 2;
  int kcol = (tid & 3) * 8;
  int wm = wv & 1, wn = wv >> 1;
  int lane15 = lane & 15, quad8 = (lane >> 4) * 8, quad = lane >> 4;

#define GR_STAGE(dA, dB, K0)                                                              \
  {                                                                                       \
    int k0_ = (K0);                                                                       \
    _Pragma("unroll") for (int r = 0; r < 2; ++r) {                                       \
      const unsigned short* gp = A + (size_t)(m0 + r * 64 + rowA) * K + k0_ + kcol;       \
      __builtin_amdgcn_global_load_lds((const __attribute__((address_space(1))) void*)gp, \
          (__attribute__((address_space(3))) void*)&(dA)[r * 2048 + wv * 512], 16, 0, 0); \
    }                                                                                     \
    _Pragma("unroll") for (int r = 0; r < 2; ++r) {                                       \
      const unsigned short* gp = Bz + (size_t)(n0 + r * 64 + rowA) * K + k0_ + kcol;      \
      __builtin_amdgcn_global_load_lds((const __attribute__((address_space(1))) void*)gp, \
          (__attribute__((address_space(3))) void*)&(dB)[r * 2048 + wv * 512], 16, 0, 0); \
    }                                                                                     \
  }

#define GR_COMPUTE(dA, dB)                                                                \
  {                                                                                       \
    bf16x8 afr[4], bfr[4];                                                                \
    _Pragma("unroll") for (int mi = 0; mi < 4; ++mi)                                      \
      afr[mi] = *(const bf16x8*)&(dA)[(wm * 64 + mi * 16 + lane15) * 32 + quad8];         \
    _Pragma("unroll") for (int ni = 0; ni < 4; ++ni)                                      \
      bfr[ni] = *(const bf16x8*)&(dB)[(wn * 64 + ni * 16 + lane15) * 32 + quad8];         \
    _Pragma("unroll") for (int mi = 0; mi < 4; ++mi)                                      \
      _Pragma("unroll") for (int ni = 0; ni < 4; ++ni)                                    \
        acc[mi][ni] =                                                                     \
            __builtin_amdgcn_mfma_f32_16x16x32_bf16(afr[mi], bfr[ni], acc[mi][ni], 0, 0, 0); \
  }

  int nst = K >> 5;  // 8: even
  GR_STAGE(sA0, sB0, 0);
  for (int t = 0; t < nst; t += 2) {
    GR_STAGE(sA1, sB1, (t + 1) * 32);
    asm volatile("s_waitcnt vmcnt(4)" ::: "memory");
    __builtin_amdgcn_s_barrier();
    GR_COMPUTE(sA0, sB0);
    __builtin_amdgcn_s_barrier();
    if (t + 2 < nst) {
      GR_STAGE(sA0, sB0, (t + 2) * 32);
      asm volatile("s_waitcnt vmcnt(4)" ::: "memory");
    } else {
      asm volatile("s_waitcnt vmcnt(0)" ::: "memory");
    }
    __builtin_amdgcn_s_barrier();
    GR_COMPUTE(sA1, sB1);
    __builtin_amdgcn_s_barrier();
  }
#undef GR_STAGE
#undef GR_COMPUTE

  float* outF = outp + (size_t)z * bStrideOut;
  const float* res = resid + (size_t)z * bStrideOut;
  int trow = tid >> 3;
  int tcol = (tid & 7) * 4;
  int growBase = m0 + (trow >> 4) * 64 + (trow & 15);
#pragma unroll
  for (int mi = 0; mi < 4; ++mi) {
    __syncthreads();
#pragma unroll
    for (int ni = 0; ni < 4; ++ni)
#pragma unroll
      for (int reg = 0; reg < 4; ++reg)
        tbuf[(wm * 16 + quad * 4 + reg) * 132 + wn * 64 + ni * 16 + lane15] = acc[mi][ni][reg];
    __syncthreads();
    int gr = growBase + mi * 16;
    float sh = shift3[gr];
    const float* rp = res + (size_t)gr * N + n0 + tcol;
    float* op = outF + (size_t)gr * N + n0 + tcol;
    const float* lp = &tbuf[trow * 132 + tcol];
#pragma unroll
    for (int j = 0; j < 4; ++j) {
      float4 rv = *(const float4*)(rp + j * 32);
      float4 lv = *(const float4*)(lp + j * 32);
      float4 ov;
      ov.x = fmaxf(lv.x + sh + rv.x, 0.f);
      ov.y = fmaxf(lv.y + sh + rv.y, 0.f);
      ov.z = fmaxf(lv.z + sh + rv.z, 0.f);
      ov.w = fmaxf(lv.w + sh + rv.w, 0.f);
      *(float4*)(op + j * 32) = ov;
    }
  }
}

// ---------------- offset conv as MFMA GEMM over padded act1P, T4 pipeline ----------------
__global__ __launch_bounds__(256) void off_gemm(const unsigned short* __restrict__ actP,
                                                const unsigned short* __restrict__ wob,
                                                const float* __restrict__ boff,
                                                float* __restrict__ offsP) {
  __shared__ __align__(16) unsigned short sA0[4096];
  __shared__ __align__(16) unsigned short sB0[2048];
  __shared__ __align__(16) unsigned short sA1[4096];
  __shared__ __align__(16) unsigned short sB1[2048];
  int tid = threadIdx.x, lane = tid & 63, wv = tid >> 6;
  int m0 = blockIdx.x * 64;
  int lane15 = lane & 15, quad8 = (lane >> 4) * 8;
  int rowA = tid >> 3;
  int kc = (tid & 7) * 8;

  const unsigned short* baseA[2];
#pragma unroll
  for (int r = 0; r < 2; ++r) {
    int row = m0 + r * 32 + rowA;
    int b = row >> 12, p = row & 4095;
    baseA[r] = actP + (((size_t)(b * 68) + (p >> 6) + 2) * 68 + (p & 63) + 2) * 256 + kc;
  }
  const unsigned short* baseB = wob + (size_t)rowA * 2304 + kc;

  f32x4 acc[2] = {};

#define OG_STAGE(dA, dB, S)                                                               \
  {                                                                                       \
    int s_ = (S); int kk_ = s_ >> 2; int c0_ = (s_ & 3) * 64;                             \
    long shift_ = (long)(((kk_ / 3) * 2 - 2) * 68 + ((kk_ % 3) * 2 - 2));                 \
    _Pragma("unroll") for (int r = 0; r < 2; ++r) {                                       \
      const unsigned short* gp = baseA[r] + shift_ * 256 + c0_;                           \
      __builtin_amdgcn_global_load_lds((const __attribute__((address_space(1))) void*)gp, \
          (__attribute__((address_space(3))) void*)&(dA)[r * 2048 + wv * 512], 16, 0, 0); \
    }                                                                                     \
    {                                                                                     \
      const unsigned short* gp = baseB + kk_ * 256 + c0_;                                 \
      __builtin_amdgcn_global_load_lds((const __attribute__((address_space(1))) void*)gp, \
          (__attribute__((address_space(3))) void*)&(dB)[wv * 512], 16, 0, 0);            \
    }                                                                                     \
  }

#define OG_COMPUTE(dA, dB)                                                                \
  {                                                                                       \
    bf16x8 afr[2], bfr[2][2];                                                             \
    _Pragma("unroll") for (int kq = 0; kq < 2; ++kq) {                                    \
      afr[kq] = *(const bf16x8*)&(dA)[(wv * 16 + lane15) * 64 + kq * 32 + quad8];         \
      _Pragma("unroll") for (int ni = 0; ni < 2; ++ni)                                    \
        bfr[kq][ni] = *(const bf16x8*)&(dB)[(ni * 16 + lane15) * 64 + kq * 32 + quad8];   \
    }                                                                                     \
    _Pragma("unroll") for (int kq = 0; kq < 2; ++kq)                                      \
      _Pragma("unroll") for (int ni = 0; ni < 2; ++ni)                                    \
        acc[ni] = __builtin_amdgcn_mfma_f32_16x16x32_bf16(afr[kq], bfr[kq][ni], acc[ni], 0, 0, 0); \
  }

  OG_STAGE(sA0, sB0, 0);
  for (int s = 0; s < 36; s += 2) {
    OG_STAGE(sA1, sB1, s + 1);
    asm volatile("s_waitcnt vmcnt(3)" ::: "memory");
    __builtin_amdgcn_s_barrier();
    OG_COMPUTE(sA0, sB0);
    __builtin_amdgcn_s_barrier();
    if (s + 2 < 36) {
      OG_STAGE(sA0, sB0, s + 2);
      asm volatile("s_waitcnt vmcnt(3)" ::: "memory");
    } else {
      asm volatile("s_waitcnt vmcnt(0)" ::: "memory");
    }
    __builtin_amdgcn_s_barrier();
    OG_COMPUTE(sA1, sB1);
    __builtin_amdgcn_s_barrier();
  }
#undef OG_STAGE
#undef OG_COMPUTE

#pragma unroll
  for (int ni = 0; ni < 2; ++ni) {
    int o = ni * 16 + lane15;
    if (o < 18) {
      float bo = boff[o];
#pragma unroll
      for (int reg = 0; reg < 4; ++reg) {
        int row = m0 + wv * 16 + (lane >> 4) * 4 + reg;
        offsP[(size_t)row * 18 + o] = acc[ni][reg] + bo;
      }
    }
  }
}

// ---------------- bilinear im2col, vectorized: 32 lanes x 8ch per pixel ----------------
__global__ __launch_bounds__(256) void deform_sample(const unsigned short* __restrict__ act1T,
                                                     const float* __restrict__ offsP,
                                                     unsigned short* __restrict__ S) {
  int g = threadIdx.x >> 5, t = threadIdx.x & 31;
  int idx = blockIdx.x * 8 + g;
  int b = idx >> 12, p = idx & 4095;
  int h = p >> 6, w = p & 63;
  const unsigned short* actb = act1T + (size_t)b * 4096 * 256 + t * 8;
  unsigned short* Sp = S + (size_t)idx * 2304 + t * 8;
  float ov = (t < 18) ? offsP[(size_t)idx * 18 + t] : 0.f;
#pragma unroll
  for (int kk = 0; kk < 9; ++kk) {
    float offy = __shfl(ov, 2 * kk, 32);
    float offx = __shfl(ov, 2 * kk + 1, 32);
    float py = (float)(h + (kk / 3) * 2 - 2) + offy;
    float px = (float)(w + (kk % 3) * 2 - 2) + offx;
    float fy = floorf(py), fx = floorf(px);
    int y0 = (int)fy, x0 = (int)fx;
    float wy = py - fy, wx = px - fx;
    bool yv0 = (y0 >= 0 && y0 < 64), yv1 = (y0 >= -1 && y0 < 63);
    bool xv0 = (x0 >= 0 && x0 < 64), xv1 = (x0 >= -1 && x0 < 63);
    const unsigned short* cb = actb + (y0 * 64 + x0) * 256;
    uint4 q00{0,0,0,0}, q01{0,0,0,0}, q10{0,0,0,0}, q11{0,0,0,0};
    if (yv0 && xv0) q00 = *(const uint4*)(cb);
    if (yv0 && xv1) q01 = *(const uint4*)(cb + 256);
    if (yv1 && xv0) q10 = *(const uint4*)(cb + 64 * 256);
    if (yv1 && xv1) q11 = *(const uint4*)(cb + 64 * 256 + 256);
    float w00 = (1.f - wy) * (1.f - wx), w01 = (1.f - wy) * wx;
    float w10 = wy * (1.f - wx), w11 = wy * wx;
    unsigned u00[4] = {q00.x, q00.y, q00.z, q00.w};
    unsigned u01[4] = {q01.x, q01.y, q01.z, q01.w};
    unsigned u10[4] = {q10.x, q10.y, q10.z, q10.w};
    unsigned u11[4] = {q11.x, q11.y, q11.z, q11.w};
    unsigned out[4];
#pragma unroll
    for (int j = 0; j < 4; ++j) {
      float lo = bf2f((unsigned short)(u00[j] & 0xffffu)) * w00 +
                 bf2f((unsigned short)(u01[j] & 0xffffu)) * w01 +
                 bf2f((unsigned short)(u10[j] & 0xffffu)) * w10 +
                 bf2f((unsigned short)(u11[j] & 0xffffu)) * w11;
      float hi = bf2f((unsigned short)(u00[j] >> 16)) * w00 +
                 bf2f((unsigned short)(u01[j] >> 16)) * w01 +
                 bf2f((unsigned short)(u10[j] >> 16)) * w10 +
                 bf2f((unsigned short)(u11[j] >> 16)) * w11;
      out[j] = (unsigned)f2bf(lo) | ((unsigned)f2bf(hi) << 16);
    }
    *(uint4*)(Sp + kk * 256) = uint4{out[0], out[1], out[2], out[3]};
  }
}

extern "C" void kernel_launch(void* const* d_in, const int* in_sizes, int n_in,
                              void* d_out, int out_size, void* d_ws, size_t ws_size,
                              hipStream_t stream) {
  const float* x      = (const float*)d_in[0];
  const float* w1     = (const float*)d_in[1];
  const float* gamma1 = (const float*)d_in[2];
  const float* beta1  = (const float*)d_in[3];
  const float* mean1  = (const float*)d_in[4];
  const float* var1   = (const float*)d_in[5];
  const float* woff   = (const float*)d_in[6];
  const float* boff   = (const float*)d_in[7];
  const float* w2     = (const float*)d_in[8];
  const float* bconv2 = (const float*)d_in[9];
  const float* gamma2 = (const float*)d_in[10];
  const float* beta2  = (const float*)d_in[11];
  const float* mean2  = (const float*)d_in[12];
  const float* var2   = (const float*)d_in[13];
  const float* w3     = (const float*)d_in[14];
  const float* gamma3 = (const float*)d_in[15];
  const float* beta3  = (const float*)d_in[16];
  const float* mean3  = (const float*)d_in[17];
  const float* var3   = (const float*)d_in[18];

  char* ws = (char*)d_ws;
  unsigned short* act1T = (unsigned short*)(ws + 33554432);      //  8,388,608
  unsigned short* act2T = (unsigned short*)(ws + 41943040);      //  8,388,608
  unsigned short* S     = (unsigned short*)(ws + 50331648);      // 75,497,472 (ends 125,829,120)
  float*          offs  = (float*)(ws + 125829120);              //  1,179,648
  unsigned short* w1b   = (unsigned short*)(ws + 127008768);     //    524,288
  unsigned short* w2r   = (unsigned short*)(ws + 127533056);     //  1,179,648
  unsigned short* w3b   = (unsigned short*)(ws + 128712704);     //    524,288
  float*          bnS1  = (float*)(ws + 129236992);              //      1,024
  float*          bnH1  = (float*)(ws + 129238016);              //      1,024
  float*          bnS2  = (float*)(ws + 129239040);              //      1,024
  float*          bnH2  = (float*)(ws + 129240064);              //      1,024
  float*          shift3= (float*)(ws + 129241088);              //      4,096
  // aliased (non-overlapping lifetimes):
  unsigned short* act1P = S;                                  // 9.47 MB at S base; dead before S written
  unsigned short* part1 = (unsigned short*)(ws + 62914560);   // 2x8 MB bf16, in S region after act1P
  unsigned short* part2 = (unsigned short*)ws;                // 2x8 MB bf16 at ws base (xT eliminated)
  unsigned short* wob   = act2T;                              // 147 KB; dead before epi_bn2 writes act2T

  prep_all<<<6957, 256, 0, stream>>>(w1, w2, woff, w3,
                                     gamma1, beta1, mean1, var1,
                                     gamma2, beta2, mean2, var2, bconv2,
                                     gamma3, beta3, mean3, var3,
                                     w1b, w2r, (uint4*)act1P, wob, w3b, shift3,
                                     bnS1, bnH1, bnS2, bnH2);

  // GEMM1 (K=1024) with fused x-transpose, split x2 -> bf16 partials -> BN1+ReLU epilogue
  gemm1_x<<<dim3(2, 128, 2), 256, 0, stream>>>(x, w1b, part1, 512);
  epi_bn<2, 1><<<2048, 256, 0, stream>>>(part1, bnS1, bnH1, act1T, act1P);

  off_gemm<<<256, 256, 0, stream>>>(act1P, wob, boff, offs);
  deform_sample<<<dim3(2048), 256, 0, stream>>>(act1T, offs, S);

  // GEMM2 (K=2304) split x2 -> bf16 partials -> bias+BN2+ReLU epilogue
  gemm_split<<<dim3(2, 128, 2), 256, 0, stream>>>(S, w2r, part2, 16384, 256, 2304, 1152);
  epi_bn<2, 0><<<2048, 256, 0, stream>>>(part2, bnS2, bnH2, act2T, nullptr);

  // GEMM3: out = relu(w3s @ act2T^T + shift3 + x)
  gemm_res<<<dim3(32, 8, 4), 256, 0, stream>>>(w3b, act2T, (float*)d_out, shift3, x,
                                               1024, 4096, 256, 4096L * 256, 4194304L);
}

// Round 5
// 276.513 us; speedup vs baseline: 1.1014x; 1.0146x over previous
//
#include <hip/hip_runtime.h>

#define EPS_BN 1e-5f

typedef __bf16 bf16x8 __attribute__((ext_vector_type(8)));
typedef float f32x4 __attribute__((ext_vector_type(4)));

__device__ __forceinline__ unsigned short f2bf(float f) {
  union { float f; unsigned u; } v; v.f = f;
  unsigned r = v.u + 0x7fffu + ((v.u >> 16) & 1u);
  return (unsigned short)(r >> 16);
}
__device__ __forceinline__ float bf2f(unsigned short h) {
  union { unsigned u; float f; } v; v.u = ((unsigned)h) << 16;
  return v.f;
}

// ---------------- fused prep ----------------
__global__ __launch_bounds__(256) void prep_all(
    const float* __restrict__ w1, const float* __restrict__ w2, const float* __restrict__ woff,
    const float* __restrict__ w3,
    const float* g1, const float* b1, const float* m1, const float* v1,
    const float* g2, const float* b2, const float* m2, const float* v2, const float* bconv2,
    const float* g3, const float* b3, const float* m3, const float* v3,
    unsigned short* __restrict__ w1b, unsigned short* __restrict__ w2r,
    uint4* __restrict__ act1Pz, unsigned short* __restrict__ wob,
    unsigned short* __restrict__ w3b, float* __restrict__ shift3,
    float* s1, float* h1, float* s2, float* h2) {
  int bid = blockIdx.x, tid = threadIdx.x;
  if (bid < 1024) {
    int i = bid * 256 + tid;
    w1b[i] = f2bf(w1[i]);
  } else if (bid < 3328) {
    int i = (bid - 1024) * 256 + tid;
    int o = i / 2304, r = i % 2304;
    int kk = r / 256, c = r % 256;
    w2r[i] = f2bf(w2[(size_t)o * 2304 + c * 9 + kk]);
  } else if (bid < 5640) {
    int i = (bid - 3328) * 256 + tid;
    if (i < 591872) act1Pz[i] = uint4{0, 0, 0, 0};
  } else if (bid < 5928) {
    int i = (bid - 5640) * 256 + tid;
    int o = i / 2304, r = i % 2304;
    int kk = r / 256, c = r % 256;
    wob[i] = (o < 18) ? f2bf(woff[(size_t)o * 2304 + c * 9 + kk]) : (unsigned short)0;
  } else if (bid < 6952) {
    int i = (bid - 5928) * 256 + tid;
    int o = i >> 8;
    float sc = rsqrtf(v3[o] + EPS_BN) * g3[o];
    w3b[i] = f2bf(w3[i] * sc);
  } else if (bid < 6956) {
    int c = (bid - 6952) * 256 + tid;
    float sc = rsqrtf(v3[c] + EPS_BN) * g3[c];
    shift3[c] = b3[c] - m3[c] * sc;
  } else {
    int c = tid;
    float sc1 = rsqrtf(v1[c] + EPS_BN) * g1[c];
    s1[c] = sc1; h1[c] = b1[c] - m1[c] * sc1;
    float sc2 = rsqrtf(v2[c] + EPS_BN) * g2[c];
    s2[c] = sc2; h2[c] = b2[c] + (bconv2[c] - m2[c]) * sc2;
  }
}

// ---------------- GEMM1 with fused x-transpose: A staged from f32 x (c-major) ----------------
// Swizzled LDS (slot ^= row&3 within 64B rows) on A ds_write, B staging source, and reads.
__global__ __launch_bounds__(256) void gemm1_x(
    const float* __restrict__ x, const unsigned short* __restrict__ Bm,
    unsigned short* __restrict__ part, int KH) {
  __shared__ __align__(16) char blob[16896];              // sA0|sB0, tbuf aliases
  __shared__ __align__(16) unsigned short sA1[4096];
  __shared__ __align__(16) unsigned short sB1[4096];
  unsigned short* sA0 = (unsigned short*)blob;
  unsigned short* sB0 = (unsigned short*)(blob + 8192);
  float* tbuf = (float*)blob;                             // epilogue only
  int tid = threadIdx.x, lane = tid & 63, wv = tid >> 6;
  int z = blockIdx.z;
  int m0 = blockIdx.y * 128, n0 = blockIdx.x * 128;
  f32x4 acc[4][4] = {};
  // B staging mapping (pre-swizzled source col)
  int rowB = tid >> 2;
  int kcolBs = (((tid & 3) ^ (rowB & 3))) * 8;
  // A staging mapping: 2 threads/row, 16 ch each; swizzled write slots
  int px = tid & 127, chalf = tid >> 7;
  int s0w = (chalf * 2) ^ (px & 3), s1w = (chalf * 2 + 1) ^ (px & 3);
  int bb = m0 >> 12, p0 = m0 & 4095;
  const float* xa = x + (size_t)bb * 4194304 + (size_t)(chalf * 16) * 4096 + (p0 + px);
  int wm = wv & 1, wn = wv >> 1;
  int lane15 = lane & 15, quad = lane >> 4, l3 = lane & 3;

  float va[16];

#define G1_ISSUE_A(K0)                                                                    \
  {                                                                                       \
    const float* xp = xa + (size_t)(K0) * 4096;                                           \
    _Pragma("unroll") for (int j = 0; j < 16; ++j) va[j] = xp[(size_t)j * 4096];          \
  }

#define G1_ISSUE_B(DB, K0)                                                                \
  {                                                                                       \
    _Pragma("unroll") for (int r = 0; r < 2; ++r) {                                       \
      const unsigned short* gp = Bm + (size_t)(n0 + r * 64 + rowB) * 1024 + (K0) + kcolBs;\
      __builtin_amdgcn_global_load_lds((const __attribute__((address_space(1))) void*)gp, \
          (__attribute__((address_space(3))) void*)&(DB)[r * 2048 + wv * 512], 16, 0, 0); \
    }                                                                                     \
  }

#define G1_CVT_WRITE(DA)                                                                  \
  {                                                                                       \
    unsigned o8[8];                                                                       \
    _Pragma("unroll") for (int j = 0; j < 8; ++j)                                         \
      o8[j] = (unsigned)f2bf(va[2 * j]) | ((unsigned)f2bf(va[2 * j + 1]) << 16);          \
    *(uint4*)((DA) + px * 32 + s0w * 8) = uint4{o8[0], o8[1], o8[2], o8[3]};              \
    *(uint4*)((DA) + px * 32 + s1w * 8) = uint4{o8[4], o8[5], o8[6], o8[7]};              \
  }

#define G1_COMPUTE(DA, DB)                                                                \
  {                                                                                       \
    bf16x8 afr[4], bfr[4];                                                                \
    _Pragma("unroll") for (int mi = 0; mi < 4; ++mi)                                      \
      afr[mi] = *(const bf16x8*)&(DA)[(wm * 64 + mi * 16 + lane15) * 32 + (quad ^ l3) * 8]; \
    _Pragma("unroll") for (int ni = 0; ni < 4; ++ni)                                      \
      bfr[ni] = *(const bf16x8*)&(DB)[(wn * 64 + ni * 16 + lane15) * 32 + (quad ^ l3) * 8]; \
    _Pragma("unroll") for (int mi = 0; mi < 4; ++mi)                                      \
      _Pragma("unroll") for (int ni = 0; ni < 4; ++ni)                                    \
        acc[mi][ni] =                                                                     \
            __builtin_amdgcn_mfma_f32_16x16x32_bf16(afr[mi], bfr[ni], acc[mi][ni], 0, 0, 0); \
  }

#define G1_BODY(K0, AC, BC, AN, BN_)                                                      \
  {                                                                                       \
    G1_ISSUE_A(K0);                                                                       \
    G1_ISSUE_B(BN_, K0);                                                                  \
    asm volatile("s_waitcnt vmcnt(18)" ::: "memory");                                     \
    asm volatile("s_waitcnt lgkmcnt(0)" ::: "memory");                                    \
    __builtin_amdgcn_s_barrier();                                                         \
    G1_COMPUTE(AC, BC);                                                                   \
    asm volatile("s_waitcnt vmcnt(2)" ::: "memory");                                      \
    G1_CVT_WRITE(AN);                                                                     \
    __builtin_amdgcn_s_barrier();                                                         \
  }

  int kbase = z * KH;
  int nst = KH >> 5;  // 16: even
  G1_ISSUE_A(kbase);
  G1_ISSUE_B(sB0, kbase);
  asm volatile("s_waitcnt vmcnt(2)" ::: "memory");
  G1_CVT_WRITE(sA0);
  for (int t = 0; t + 2 < nst; t += 2) {
    G1_BODY(kbase + (t + 1) * 32, sA0, sB0, sA1, sB1);
    G1_BODY(kbase + (t + 2) * 32, sA1, sB1, sA0, sB0);
  }
  G1_BODY(kbase + (nst - 1) * 32, sA0, sB0, sA1, sB1);
  asm volatile("s_waitcnt vmcnt(0)" ::: "memory");
  asm volatile("s_waitcnt lgkmcnt(0)" ::: "memory");
  __builtin_amdgcn_s_barrier();
  G1_COMPUTE(sA1, sB1);
#undef G1_ISSUE_A
#undef G1_ISSUE_B
#undef G1_CVT_WRITE
#undef G1_COMPUTE
#undef G1_BODY

  // vectorized epilogue -> z-partial
  unsigned short* outH = part + (size_t)z * 16384 * 256;
  int trow = tid >> 3;
  int tcol16 = (tid & 7) * 16;
  int growBase = m0 + (trow >> 4) * 64 + (trow & 15);
#pragma unroll
  for (int mi = 0; mi < 4; ++mi) {
    __syncthreads();
#pragma unroll
    for (int ni = 0; ni < 4; ++ni)
#pragma unroll
      for (int reg = 0; reg < 4; ++reg)
        tbuf[(wm * 16 + quad * 4 + reg) * 132 + wn * 64 + ni * 16 + lane15] = acc[mi][ni][reg];
    __syncthreads();
    int gr = growBase + mi * 16;
    const float* lp = &tbuf[trow * 132 + tcol16];
    unsigned o[8];
#pragma unroll
    for (int j = 0; j < 8; ++j)
      o[j] = (unsigned)f2bf(lp[2 * j]) | ((unsigned)f2bf(lp[2 * j + 1]) << 16);
    unsigned short* op = outH + (size_t)gr * 256 + n0 + tcol16;
    *(uint4*)(op) = uint4{o[0], o[1], o[2], o[3]};
    *(uint4*)(op + 8) = uint4{o[4], o[5], o[6], o[7]};
  }
}

// ---------------- GEMM2: BK=64 superstep, swizzled LDS (slot ^= row&7), vmcnt(8) ----------------
__global__ __launch_bounds__(256) void gemm_split(
    const unsigned short* __restrict__ A, const unsigned short* __restrict__ Bm,
    unsigned short* __restrict__ part, int M, int N, int K, int KH) {
  __shared__ __align__(16) char blob[32768];              // sA0|sB0 (16K each), tbuf aliases
  __shared__ __align__(16) unsigned short sA1[8192];
  __shared__ __align__(16) unsigned short sB1[8192];
  unsigned short* sA0 = (unsigned short*)blob;
  unsigned short* sB0 = (unsigned short*)(blob + 16384);
  float* tbuf = (float*)blob;                             // epilogue only
  int tid = threadIdx.x, lane = tid & 63, wv = tid >> 6;
  int z = blockIdx.z;
  int m0 = blockIdx.y * 128, n0 = blockIdx.x * 128;
  f32x4 acc[4][4] = {};
  int rowS = tid >> 3;               // 0..31 staging row within call
  int colS = (((tid & 7) ^ (rowS & 7))) * 8;  // pre-swizzled source col (elements)
  int wm = wv & 1, wn = wv >> 1;
  int lane15 = lane & 15, quad = lane >> 4, l7 = lane & 7;

#define GS_STAGE(dA, dB, K0)                                                              \
  {                                                                                       \
    int k0_ = (K0);                                                                       \
    _Pragma("unroll") for (int r = 0; r < 4; ++r) {                                       \
      const unsigned short* gp = A + (size_t)(m0 + r * 32 + rowS) * K + k0_ + colS;       \
      __builtin_amdgcn_global_load_lds((const __attribute__((address_space(1))) void*)gp, \
          (__attribute__((address_space(3))) void*)&(dA)[r * 2048 + wv * 512], 16, 0, 0); \
    }                                                                                     \
    _Pragma("unroll") for (int r = 0; r < 4; ++r) {                                       \
      const unsigned short* gp = Bm + (size_t)(n0 + r * 32 + rowS) * K + k0_ + colS;      \
      __builtin_amdgcn_global_load_lds((const __attribute__((address_space(1))) void*)gp, \
          (__attribute__((address_space(3))) void*)&(dB)[r * 2048 + wv * 512], 16, 0, 0); \
    }                                                                                     \
  }

#define GS_COMPUTE(dA, dB)                                                                \
  {                                                                                       \
    _Pragma("unroll") for (int kq = 0; kq < 2; ++kq) {                                    \
      bf16x8 afr[4], bfr[4];                                                              \
      _Pragma("unroll") for (int mi = 0; mi < 4; ++mi)                                    \
        afr[mi] = *(const bf16x8*)&(dA)[(wm * 64 + mi * 16 + lane15) * 64 +               \
                                        ((kq * 4 + quad) ^ l7) * 8];                      \
      _Pragma("unroll") for (int ni = 0; ni < 4; ++ni)                                    \
        bfr[ni] = *(const bf16x8*)&(dB)[(wn * 64 + ni * 16 + lane15) * 64 +               \
                                        ((kq * 4 + quad) ^ l7) * 8];                      \
      _Pragma("unroll") for (int mi = 0; mi < 4; ++mi)                                    \
        _Pragma("unroll") for (int ni = 0; ni < 4; ++ni)                                  \
          acc[mi][ni] =                                                                   \
              __builtin_amdgcn_mfma_f32_16x16x32_bf16(afr[mi], bfr[ni], acc[mi][ni], 0, 0, 0); \
    }                                                                                     \
  }

  int kbase = z * KH;
  int nst = KH >> 6;  // 18 (GEMM2 z=2): even
  GS_STAGE(sA0, sB0, kbase);
  for (int t = 0; t < nst; t += 2) {
    GS_STAGE(sA1, sB1, kbase + (t + 1) * 64);
    asm volatile("s_waitcnt vmcnt(8)" ::: "memory");
    __builtin_amdgcn_s_barrier();
    GS_COMPUTE(sA0, sB0);
    __builtin_amdgcn_s_barrier();
    if (t + 2 < nst) {
      GS_STAGE(sA0, sB0, kbase + (t + 2) * 64);
      asm volatile("s_waitcnt vmcnt(8)" ::: "memory");
    } else {
      asm volatile("s_waitcnt vmcnt(0)" ::: "memory");
    }
    __builtin_amdgcn_s_barrier();
    GS_COMPUTE(sA1, sB1);
    __builtin_amdgcn_s_barrier();
  }
#undef GS_STAGE
#undef GS_COMPUTE

  // vectorized epilogue: LDS-transpose each 32-row chunk, pack 16ch/thread -> 2 uint4 stores
  unsigned short* outH = part + (size_t)z * M * N;
  int trow = tid >> 3;              // 0..31
  int tcol16 = (tid & 7) * 16;      // 0..112
  int growBase = m0 + (trow >> 4) * 64 + (trow & 15);
#pragma unroll
  for (int mi = 0; mi < 4; ++mi) {
    __syncthreads();
#pragma unroll
    for (int ni = 0; ni < 4; ++ni)
#pragma unroll
      for (int reg = 0; reg < 4; ++reg)
        tbuf[(wm * 16 + quad * 4 + reg) * 132 + wn * 64 + ni * 16 + lane15] = acc[mi][ni][reg];
    __syncthreads();
    int gr = growBase + mi * 16;
    const float* lp = &tbuf[trow * 132 + tcol16];
    unsigned o[8];
#pragma unroll
    for (int j = 0; j < 8; ++j)
      o[j] = (unsigned)f2bf(lp[2 * j]) | ((unsigned)f2bf(lp[2 * j + 1]) << 16);
    unsigned short* op = outH + (size_t)gr * 256 + n0 + tcol16;
    *(uint4*)(op) = uint4{o[0], o[1], o[2], o[3]};
    *(uint4*)(op + 8) = uint4{o[4], o[5], o[6], o[7]};
  }
}

// ---------------- epilogue: sum NS bf16 partials, folded BN + ReLU -> bf16 (+opt padded copy) ----------------
template <int NS, int PAD>
__global__ __launch_bounds__(256) void epi_bn(const unsigned short* __restrict__ part,
                                              const float* __restrict__ scale,
                                              const float* __restrict__ shift,
                                              unsigned short* __restrict__ outT,
                                              unsigned short* __restrict__ outP) {
  int gid = blockIdx.x * 256 + threadIdx.x;   // 16384*32
  int row = gid >> 5, c0 = (gid & 31) * 8;
  float v[8] = {};
#pragma unroll
  for (int s = 0; s < NS; ++s) {
    uint4 q = *(const uint4*)(part + (size_t)s * 16384 * 256 + (size_t)row * 256 + c0);
    unsigned u[4] = {q.x, q.y, q.z, q.w};
#pragma unroll
    for (int j = 0; j < 4; ++j) {
      v[2 * j]     += bf2f((unsigned short)(u[j] & 0xffffu));
      v[2 * j + 1] += bf2f((unsigned short)(u[j] >> 16));
    }
  }
  float sc[8], sh[8];
  *(float4*)&sc[0] = *(const float4*)(scale + c0); *(float4*)&sc[4] = *(const float4*)(scale + c0 + 4);
  *(float4*)&sh[0] = *(const float4*)(shift + c0); *(float4*)&sh[4] = *(const float4*)(shift + c0 + 4);
  unsigned o[4];
#pragma unroll
  for (int j = 0; j < 4; ++j) {
    float lo = fmaxf(v[2 * j] * sc[2 * j] + sh[2 * j], 0.f);
    float hi = fmaxf(v[2 * j + 1] * sc[2 * j + 1] + sh[2 * j + 1], 0.f);
    o[j] = (unsigned)f2bf(lo) | ((unsigned)f2bf(hi) << 16);
  }
  uint4 pk{o[0], o[1], o[2], o[3]};
  *(uint4*)(outT + (size_t)row * 256 + c0) = pk;
  if constexpr (PAD) {
    int bb = row >> 12, p = row & 4095;
    *(uint4*)(outP + (((size_t)(bb * 68) + (p >> 6) + 2) * 68 + (p & 63) + 2) * 256 + c0) = pk;
  }
}

// ---------------- final GEMM (1x1 conv #3), BN3 pre-folded, T4 pipeline + swizzle ----------------
__global__ __launch_bounds__(256) void gemm_res(
    const unsigned short* __restrict__ A, const unsigned short* __restrict__ Bm,
    float* __restrict__ outp, const float* __restrict__ shift3,
    const float* __restrict__ resid, int M, int N, int K, long bStrideB, long bStrideOut) {
  __shared__ __align__(16) char blob[16896];
  __shared__ __align__(16) unsigned short sA1[4096];
  __shared__ __align__(16) unsigned short sB1[4096];
  unsigned short* sA0 = (unsigned short*)blob;
  unsigned short* sB0 = (unsigned short*)(blob + 8192);
  float* tbuf = (float*)blob;
  int tid = threadIdx.x, lane = tid & 63, wv = tid >> 6;
  int z = blockIdx.z;
  const unsigned short* Bz = Bm + (size_t)z * bStrideB;
  int m0 = blockIdx.y * 128, n0 = blockIdx.x * 128;
  f32x4 acc[4][4] = {};
  int rowA = tid >> 2;
  int kcolS = (((tid & 3) ^ (rowA & 3))) * 8;   // pre-swizzled source col
  int wm = wv & 1, wn = wv >> 1;
  int lane15 = lane & 15, quad = lane >> 4, l3 = lane & 3;

#define GR_STAGE(dA, dB, K0)                                                              \
  {                                                                                       \
    int k0_ = (K0);                                                                       \
    _Pragma("unroll") for (int r = 0; r < 2; ++r) {                                       \
      const unsigned short* gp = A + (size_t)(m0 + r * 64 + rowA) * K + k0_ + kcolS;      \
      __builtin_amdgcn_global_load_lds((const __attribute__((address_space(1))) void*)gp, \
          (__attribute__((address_space(3))) void*)&(dA)[r * 2048 + wv * 512], 16, 0, 0); \
    }                                                                                     \
    _Pragma("unroll") for (int r = 0; r < 2; ++r) {                                       \
      const unsigned short* gp = Bz + (size_t)(n0 + r * 64 + rowA) * K + k0_ + kcolS;     \
      __builtin_amdgcn_global_load_lds((const __attribute__((address_space(1))) void*)gp, \
          (__attribute__((address_space(3))) void*)&(dB)[r * 2048 + wv * 512], 16, 0, 0); \
    }                                                                                     \
  }

#define GR_COMPUTE(dA, dB)                                                                \
  {                                                                                       \
    bf16x8 afr[4], bfr[4];                                                                \
    _Pragma("unroll") for (int mi = 0; mi < 4; ++mi)                                      \
      afr[mi] = *(const bf16x8*)&(dA)[(wm * 64 + mi * 16 + lane15) * 32 + (quad ^ l3) * 8]; \
    _Pragma("unroll") for (int ni = 0; ni < 4; ++ni)                                      \
      bfr[ni] = *(const bf16x8*)&(dB)[(wn * 64 + ni * 16 + lane15) * 32 + (quad ^ l3) * 8]; \
    _Pragma("unroll") for (int mi = 0; mi < 4; ++mi)                                      \
      _Pragma("unroll") for (int ni = 0; ni < 4; ++ni)                                    \
        acc[mi][ni] =                                                                     \
            __builtin_amdgcn_mfma_f32_16x16x32_bf16(afr[mi], bfr[ni], acc[mi][ni], 0, 0, 0); \
  }

  int nst = K >> 5;  // 8: even
  GR_STAGE(sA0, sB0, 0);
  for (int t = 0; t < nst; t += 2) {
    GR_STAGE(sA1, sB1, (t + 1) * 32);
    asm volatile("s_waitcnt vmcnt(4)" ::: "memory");
    __builtin_amdgcn_s_barrier();
    GR_COMPUTE(sA0, sB0);
    __builtin_amdgcn_s_barrier();
    if (t + 2 < nst) {
      GR_STAGE(sA0, sB0, (t + 2) * 32);
      asm volatile("s_waitcnt vmcnt(4)" ::: "memory");
    } else {
      asm volatile("s_waitcnt vmcnt(0)" ::: "memory");
    }
    __builtin_amdgcn_s_barrier();
    GR_COMPUTE(sA1, sB1);
    __builtin_amdgcn_s_barrier();
  }
#undef GR_STAGE
#undef GR_COMPUTE

  float* outF = outp + (size_t)z * bStrideOut;
  const float* res = resid + (size_t)z * bStrideOut;
  int trow = tid >> 3;
  int tcol = (tid & 7) * 4;
  int growBase = m0 + (trow >> 4) * 64 + (trow & 15);
#pragma unroll
  for (int mi = 0; mi < 4; ++mi) {
    __syncthreads();
#pragma unroll
    for (int ni = 0; ni < 4; ++ni)
#pragma unroll
      for (int reg = 0; reg < 4; ++reg)
        tbuf[(wm * 16 + quad * 4 + reg) * 132 + wn * 64 + ni * 16 + lane15] = acc[mi][ni][reg];
    __syncthreads();
    int gr = growBase + mi * 16;
    float sh = shift3[gr];
    const float* rp = res + (size_t)gr * N + n0 + tcol;
    float* op = outF + (size_t)gr * N + n0 + tcol;
    const float* lp = &tbuf[trow * 132 + tcol];
#pragma unroll
    for (int j = 0; j < 4; ++j) {
      float4 rv = *(const float4*)(rp + j * 32);
      float4 lv = *(const float4*)(lp + j * 32);
      float4 ov;
      ov.x = fmaxf(lv.x + sh + rv.x, 0.f);
      ov.y = fmaxf(lv.y + sh + rv.y, 0.f);
      ov.z = fmaxf(lv.z + sh + rv.z, 0.f);
      ov.w = fmaxf(lv.w + sh + rv.w, 0.f);
      *(float4*)(op + j * 32) = ov;
    }
  }
}

// ---------------- offset conv as MFMA GEMM over padded act1P, T4 pipeline ----------------
__global__ __launch_bounds__(256) void off_gemm(const unsigned short* __restrict__ actP,
                                                const unsigned short* __restrict__ wob,
                                                const float* __restrict__ boff,
                                                float* __restrict__ offsP) {
  __shared__ __align__(16) unsigned short sA0[4096];
  __shared__ __align__(16) unsigned short sB0[2048];
  __shared__ __align__(16) unsigned short sA1[4096];
  __shared__ __align__(16) unsigned short sB1[2048];
  int tid = threadIdx.x, lane = tid & 63, wv = tid >> 6;
  int m0 = blockIdx.x * 64;
  int lane15 = lane & 15, quad8 = (lane >> 4) * 8;
  int rowA = tid >> 3;
  int kc = (tid & 7) * 8;

  const unsigned short* baseA[2];
#pragma unroll
  for (int r = 0; r < 2; ++r) {
    int row = m0 + r * 32 + rowA;
    int b = row >> 12, p = row & 4095;
    baseA[r] = actP + (((size_t)(b * 68) + (p >> 6) + 2) * 68 + (p & 63) + 2) * 256 + kc;
  }
  const unsigned short* baseB = wob + (size_t)rowA * 2304 + kc;

  f32x4 acc[2] = {};

#define OG_STAGE(dA, dB, S)                                                               \
  {                                                                                       \
    int s_ = (S); int kk_ = s_ >> 2; int c0_ = (s_ & 3) * 64;                             \
    long shift_ = (long)(((kk_ / 3) * 2 - 2) * 68 + ((kk_ % 3) * 2 - 2));                 \
    _Pragma("unroll") for (int r = 0; r < 2; ++r) {                                       \
      const unsigned short* gp = baseA[r] + shift_ * 256 + c0_;                           \
      __builtin_amdgcn_global_load_lds((const __attribute__((address_space(1))) void*)gp, \
          (__attribute__((address_space(3))) void*)&(dA)[r * 2048 + wv * 512], 16, 0, 0); \
    }                                                                                     \
    {                                                                                     \
      const unsigned short* gp = baseB + kk_ * 256 + c0_;                                 \
      __builtin_amdgcn_global_load_lds((const __attribute__((address_space(1))) void*)gp, \
          (__attribute__((address_space(3))) void*)&(dB)[wv * 512], 16, 0, 0);            \
    }                                                                                     \
  }

#define OG_COMPUTE(dA, dB)                                                                \
  {                                                                                       \
    bf16x8 afr[2], bfr[2][2];                                                             \
    _Pragma("unroll") for (int kq = 0; kq < 2; ++kq) {                                    \
      afr[kq] = *(const bf16x8*)&(dA)[(wv * 16 + lane15) * 64 + kq * 32 + quad8];         \
      _Pragma("unroll") for (int ni = 0; ni < 2; ++ni)                                    \
        bfr[kq][ni] = *(const bf16x8*)&(dB)[(ni * 16 + lane15) * 64 + kq * 32 + quad8];   \
    }                                                                                     \
    _Pragma("unroll") for (int kq = 0; kq < 2; ++kq)                                      \
      _Pragma("unroll") for (int ni = 0; ni < 2; ++ni)                                    \
        acc[ni] = __builtin_amdgcn_mfma_f32_16x16x32_bf16(afr[kq], bfr[kq][ni], acc[ni], 0, 0, 0); \
  }

  OG_STAGE(sA0, sB0, 0);
  for (int s = 0; s < 36; s += 2) {
    OG_STAGE(sA1, sB1, s + 1);
    asm volatile("s_waitcnt vmcnt(3)" ::: "memory");
    __builtin_amdgcn_s_barrier();
    OG_COMPUTE(sA0, sB0);
    __builtin_amdgcn_s_barrier();
    if (s + 2 < 36) {
      OG_STAGE(sA0, sB0, s + 2);
      asm volatile("s_waitcnt vmcnt(3)" ::: "memory");
    } else {
      asm volatile("s_waitcnt vmcnt(0)" ::: "memory");
    }
    __builtin_amdgcn_s_barrier();
    OG_COMPUTE(sA1, sB1);
    __builtin_amdgcn_s_barrier();
  }
#undef OG_STAGE
#undef OG_COMPUTE

#pragma unroll
  for (int ni = 0; ni < 2; ++ni) {
    int o = ni * 16 + lane15;
    if (o < 18) {
      float bo = boff[o];
#pragma unroll
      for (int reg = 0; reg < 4; ++reg) {
        int row = m0 + wv * 16 + (lane >> 4) * 4 + reg;
        offsP[(size_t)row * 18 + o] = acc[ni][reg] + bo;
      }
    }
  }
}

// ---------------- bilinear im2col, vectorized: 32 lanes x 8ch per pixel ----------------
__global__ __launch_bounds__(256) void deform_sample(const unsigned short* __restrict__ act1T,
                                                     const float* __restrict__ offsP,
                                                     unsigned short* __restrict__ S) {
  int g = threadIdx.x >> 5, t = threadIdx.x & 31;
  int idx = blockIdx.x * 8 + g;
  int b = idx >> 12, p = idx & 4095;
  int h = p >> 6, w = p & 63;
  const unsigned short* actb = act1T + (size_t)b * 4096 * 256 + t * 8;
  unsigned short* Sp = S + (size_t)idx * 2304 + t * 8;
  float ov = (t < 18) ? offsP[(size_t)idx * 18 + t] : 0.f;
#pragma unroll
  for (int kk = 0; kk < 9; ++kk) {
    float offy = __shfl(ov, 2 * kk, 32);
    float offx = __shfl(ov, 2 * kk + 1, 32);
    float py = (float)(h + (kk / 3) * 2 - 2) + offy;
    float px = (float)(w + (kk % 3) * 2 - 2) + offx;
    float fy = floorf(py), fx = floorf(px);
    int y0 = (int)fy, x0 = (int)fx;
    float wy = py - fy, wx = px - fx;
    bool yv0 = (y0 >= 0 && y0 < 64), yv1 = (y0 >= -1 && y0 < 63);
    bool xv0 = (x0 >= 0 && x0 < 64), xv1 = (x0 >= -1 && x0 < 63);
    const unsigned short* cb = actb + (y0 * 64 + x0) * 256;
    uint4 q00{0,0,0,0}, q01{0,0,0,0}, q10{0,0,0,0}, q11{0,0,0,0};
    if (yv0 && xv0) q00 = *(const uint4*)(cb);
    if (yv0 && xv1) q01 = *(const uint4*)(cb + 256);
    if (yv1 && xv0) q10 = *(const uint4*)(cb + 64 * 256);
    if (yv1 && xv1) q11 = *(const uint4*)(cb + 64 * 256 + 256);
    float w00 = (1.f - wy) * (1.f - wx), w01 = (1.f - wy) * wx;
    float w10 = wy * (1.f - wx), w11 = wy * wx;
    unsigned u00[4] = {q00.x, q00.y, q00.z, q00.w};
    unsigned u01[4] = {q01.x, q01.y, q01.z, q01.w};
    unsigned u10[4] = {q10.x, q10.y, q10.z, q10.w};
    unsigned u11[4] = {q11.x, q11.y, q11.z, q11.w};
    unsigned out[4];
#pragma unroll
    for (int j = 0; j < 4; ++j) {
      float lo = bf2f((unsigned short)(u00[j] & 0xffffu)) * w00 +
                 bf2f((unsigned short)(u01[j] & 0xffffu)) * w01 +
                 bf2f((unsigned short)(u10[j] & 0xffffu)) * w10 +
                 bf2f((unsigned short)(u11[j] & 0xffffu)) * w11;
      float hi = bf2f((unsigned short)(u00[j] >> 16)) * w00 +
                 bf2f((unsigned short)(u01[j] >> 16)) * w01 +
                 bf2f((unsigned short)(u10[j] >> 16)) * w10 +
                 bf2f((unsigned short)(u11[j] >> 16)) * w11;
      out[j] = (unsigned)f2bf(lo) | ((unsigned)f2bf(hi) << 16);
    }
    *(uint4*)(Sp + kk * 256) = uint4{out[0], out[1], out[2], out[3]};
  }
}

extern "C" void kernel_launch(void* const* d_in, const int* in_sizes, int n_in,
                              void* d_out, int out_size, void* d_ws, size_t ws_size,
                              hipStream_t stream) {
  const float* x      = (const float*)d_in[0];
  const float* w1     = (const float*)d_in[1];
  const float* gamma1 = (const float*)d_in[2];
  const float* beta1  = (const float*)d_in[3];
  const float* mean1  = (const float*)d_in[4];
  const float* var1   = (const float*)d_in[5];
  const float* woff   = (const float*)d_in[6];
  const float* boff   = (const float*)d_in[7];
  const float* w2     = (const float*)d_in[8];
  const float* bconv2 = (const float*)d_in[9];
  const float* gamma2 = (const float*)d_in[10];
  const float* beta2  = (const float*)d_in[11];
  const float* mean2  = (const float*)d_in[12];
  const float* var2   = (const float*)d_in[13];
  const float* w3     = (const float*)d_in[14];
  const float* gamma3 = (const float*)d_in[15];
  const float* beta3  = (const float*)d_in[16];
  const float* mean3  = (const float*)d_in[17];
  const float* var3   = (const float*)d_in[18];

  char* ws = (char*)d_ws;
  unsigned short* act1T = (unsigned short*)(ws + 33554432);      //  8,388,608
  unsigned short* act2T = (unsigned short*)(ws + 41943040);      //  8,388,608
  unsigned short* S     = (unsigned short*)(ws + 50331648);      // 75,497,472 (ends 125,829,120)
  float*          offs  = (float*)(ws + 125829120);              //  1,179,648
  unsigned short* w1b   = (unsigned short*)(ws + 127008768);     //    524,288
  unsigned short* w2r   = (unsigned short*)(ws + 127533056);     //  1,179,648
  unsigned short* w3b   = (unsigned short*)(ws + 128712704);     //    524,288
  float*          bnS1  = (float*)(ws + 129236992);              //      1,024
  float*          bnH1  = (float*)(ws + 129238016);              //      1,024
  float*          bnS2  = (float*)(ws + 129239040);              //      1,024
  float*          bnH2  = (float*)(ws + 129240064);              //      1,024
  float*          shift3= (float*)(ws + 129241088);              //      4,096
  // aliased (non-overlapping lifetimes):
  unsigned short* act1P = S;                                  // 9.47 MB at S base; dead before S written
  unsigned short* part1 = (unsigned short*)(ws + 62914560);   // 2x8 MB bf16, in S region after act1P
  unsigned short* part2 = (unsigned short*)ws;                // 2x8 MB bf16 at ws base
  unsigned short* wob   = act2T;                              // 147 KB; dead before epi_bn2 writes act2T

  prep_all<<<6957, 256, 0, stream>>>(w1, w2, woff, w3,
                                     gamma1, beta1, mean1, var1,
                                     gamma2, beta2, mean2, var2, bconv2,
                                     gamma3, beta3, mean3, var3,
                                     w1b, w2r, (uint4*)act1P, wob, w3b, shift3,
                                     bnS1, bnH1, bnS2, bnH2);

  // GEMM1 (K=1024) with fused x-transpose, split x2 -> bf16 partials -> BN1+ReLU epilogue
  gemm1_x<<<dim3(2, 128, 2), 256, 0, stream>>>(x, w1b, part1, 512);
  epi_bn<2, 1><<<2048, 256, 0, stream>>>(part1, bnS1, bnH1, act1T, act1P);

  off_gemm<<<256, 256, 0, stream>>>(act1P, wob, boff, offs);
  deform_sample<<<dim3(2048), 256, 0, stream>>>(act1T, offs, S);

  // GEMM2 (K=2304) split x2, BK=64 swizzled superstep -> bf16 partials -> bias+BN2+ReLU epilogue
  gemm_split<<<dim3(2, 128, 2), 256, 0, stream>>>(S, w2r, part2, 16384, 256, 2304, 1152);
  epi_bn<2, 0><<<2048, 256, 0, stream>>>(part2, bnS2, bnH2, act2T, nullptr);

  // GEMM3: out = relu(w3s @ act2T^T + shift3 + x)
  gemm_res<<<dim3(32, 8, 4), 256, 0, stream>>>(w3b, act2T, (float*)d_out, shift3, x,
                                               1024, 4096, 256, 4096L * 256, 4194304L);
}